// Round 1
// baseline (1005.134 us; speedup 1.0000x reference)
//
#include <hip/hip_runtime.h>
#include <math.h>

__device__ __forceinline__ float elu_f(float v) {
    return v > 0.f ? v : (expf(v) - 1.f);
}

// ---------------------------------------------------------------------------
// Conv1d (C_in=C_out=64) + bias + ELU + optional BatchNorm (eval mode).
// Grid: (n=512, t_tile). Block 256. Each block: 64 co x 64 t outputs.
// Thread: 4 co x 4 t register tile. Input window staged in LDS.
// ---------------------------------------------------------------------------
template<int K, int STRIDE, int PAD, bool DO_BN>
__global__ __launch_bounds__(256) void conv_elu_bn(
    const float* __restrict__ x, const float* __restrict__ w,
    const float* __restrict__ bias,
    const float* __restrict__ bn_g, const float* __restrict__ bn_b,
    const float* __restrict__ bn_m, const float* __restrict__ bn_v,
    float* __restrict__ y, int Lin, int Lout)
{
    constexpr int SPAN = STRIDE * 63 + K;   // input span covering 64 outputs
    __shared__ float sx[64 * SPAN];
    const int n  = blockIdx.x;
    const int t0 = blockIdx.y * 64;
    const int lo = STRIDE * t0 - PAD;
    const float* xb = x + (size_t)n * 64 * Lin;
    for (int idx = threadIdx.x; idx < 64 * SPAN; idx += 256) {
        int ci = idx / SPAN;
        int j  = idx - ci * SPAN;
        int pos = lo + j;
        sx[idx] = (pos >= 0 && pos < Lin) ? xb[ci * Lin + pos] : 0.f;
    }
    __syncthreads();

    const int tl = threadIdx.x & 15;   // t within tile (16 lanes)
    const int cg = threadIdx.x >> 4;   // 16 groups of 4 co
    float acc[4][4] = {};
    const float* wb = w + (size_t)cg * 4 * 64 * K;
    for (int ci = 0; ci < 64; ++ci) {
        float wv[4][K];
        #pragma unroll
        for (int i = 0; i < 4; ++i)
            #pragma unroll
            for (int k = 0; k < K; ++k)
                wv[i][k] = wb[(i * 64 + ci) * K + k];
        const float* srow = sx + ci * SPAN + STRIDE * tl;
        #pragma unroll
        for (int j = 0; j < 4; ++j) {
            #pragma unroll
            for (int k = 0; k < K; ++k) {
                float xv = srow[STRIDE * 16 * j + k];
                #pragma unroll
                for (int i = 0; i < 4; ++i)
                    acc[i][j] = fmaf(wv[i][k], xv, acc[i][j]);
            }
        }
    }

    #pragma unroll
    for (int i = 0; i < 4; ++i) {
        int co = cg * 4 + i;
        float bi = bias[co];
        float scale = 1.f, shift = 0.f;
        if constexpr (DO_BN) {
            float inv = bn_g[co] / sqrtf(bn_v[co] + 1e-5f);
            scale = inv;
            shift = bn_b[co] - bn_m[co] * inv;
        }
        #pragma unroll
        for (int j = 0; j < 4; ++j) {
            int t = t0 + tl + 16 * j;
            if (t < Lout) {
                float v = acc[i][j] + bi;
                v = elu_f(v);                    // ELU before BN (per reference)
                if constexpr (DO_BN) v = v * scale + shift;
                y[((size_t)n * 64 + co) * Lout + t] = v;
            }
        }
    }
}

// ---------------------------------------------------------------------------
// Avg-pool window 3 stride 2: [512,64,82] -> [512,64,40]
// ---------------------------------------------------------------------------
__global__ __launch_bounds__(256) void pool3_k(const float* __restrict__ x,
                                               float* __restrict__ y)
{
    int idx = blockIdx.x * 256 + threadIdx.x;
    if (idx >= 512 * 64 * 40) return;
    int t  = idx % 40;
    int nc = idx / 40;
    const float* xr = x + (size_t)nc * 82 + 2 * t;
    y[idx] = (xr[0] + xr[1] + xr[2]) * (1.0f / 3.0f);
}

// ---------------------------------------------------------------------------
// Attention pooling over crop dim. One block per (b,c). h: [32,16,64,35].
// out[b,c,:] = elu(sum_s alpha[s] * h[b,s,c,:]),
// alpha = softmax_s( sum_d tanh(h[b,s,c,:].W[:,d] + ab[d]) * u[d] )
// ---------------------------------------------------------------------------
__global__ __launch_bounds__(256) void attn_pool_k(
    const float* __restrict__ h, const float* __restrict__ W,
    const float* __restrict__ ab, const float* __restrict__ u,
    float* __restrict__ out)
{
    const int b = blockIdx.x >> 6;
    const int c = blockIdx.x & 63;
    __shared__ float sh[16 * 35];
    __shared__ float slog[16];
    __shared__ float sred[4];
    __shared__ float salpha[16];
    const int tid = threadIdx.x;
    for (int idx = tid; idx < 16 * 35; idx += 256) {
        int s = idx / 35, hh = idx - s * 35;
        sh[idx] = h[(((size_t)b * 16 + s) * 64 + c) * 35 + hh];
    }
    __syncthreads();
    float Wc[35];
    #pragma unroll
    for (int k = 0; k < 35; ++k) Wc[k] = W[k * 256 + tid];
    const float myb = ab[tid], myu = u[tid];
    for (int s = 0; s < 16; ++s) {
        float dot = myb;
        #pragma unroll
        for (int k = 0; k < 35; ++k) dot = fmaf(sh[s * 35 + k], Wc[k], dot);
        float val = tanhf(dot) * myu;
        #pragma unroll
        for (int off = 32; off > 0; off >>= 1) val += __shfl_down(val, off, 64);
        if ((tid & 63) == 0) sred[tid >> 6] = val;
        __syncthreads();
        if (tid == 0) slog[s] = sred[0] + sred[1] + sred[2] + sred[3];
        __syncthreads();
    }
    if (tid == 0) {
        float m = slog[0];
        for (int s = 1; s < 16; ++s) m = fmaxf(m, slog[s]);
        float sum = 0.f, e[16];
        for (int s = 0; s < 16; ++s) { e[s] = expf(slog[s] - m); sum += e[s]; }
        float inv = 1.f / sum;
        for (int s = 0; s < 16; ++s) salpha[s] = e[s] * inv;
    }
    __syncthreads();
    if (tid < 35) {
        float acc = 0.f;
        for (int s = 0; s < 16; ++s) acc = fmaf(sh[s * 35 + tid], salpha[s], acc);
        out[((size_t)b * 64 + c) * 35 + tid] = elu_f(acc);
    }
}

// ---------------------------------------------------------------------------
// Column sum over the 64 graph nodes: S[b,k] = sum_n H[b,n,k]
// ---------------------------------------------------------------------------
__global__ __launch_bounds__(256) void colsum_k(const float* __restrict__ H,
                                                float* __restrict__ S, int Kd)
{
    int b = blockIdx.x;
    int k = blockIdx.y * 256 + threadIdx.x;
    if (k >= Kd) return;
    const float* Hb = H + (size_t)b * 64 * Kd + k;
    float s = 0.f;
    for (int n = 0; n < 64; ++n) s += Hb[(size_t)n * Kd];
    S[b * Kd + k] = s;
}

// ---------------------------------------------------------------------------
// GIN matmul: Y[b,n,o] = act( sum_k (H[b,n,k] (+S[b,k])) * W[k,o] + B[o] )
// Block computes a 64n x 64o tile for one b. Thread: 4x4 register tile.
// ---------------------------------------------------------------------------
template<bool AGG, bool RELU>
__global__ __launch_bounds__(256) void gin_gemm(
    const float* __restrict__ H, const float* __restrict__ S,
    const float* __restrict__ W, const float* __restrict__ Bb,
    float* __restrict__ Y, int Kin, int Kout)
{
    const int b  = blockIdx.x;
    const int o0 = blockIdx.y * 64;
    __shared__ float sH[64][68];
    __shared__ float sW[64][68];
    const int tid = threadIdx.x;
    const int nt = tid & 15;
    const int og = tid >> 4;
    float acc[4][4] = {};
    const int nch = (Kin + 63) >> 6;
    for (int kc = 0; kc < nch; ++kc) {
        const int kbase = kc * 64;
        for (int idx = tid; idx < 4096; idx += 256) {
            int r = idx >> 6, cidx = idx & 63;
            int k = kbase + cidx;
            float v = 0.f;
            if (k < Kin) {
                v = H[((size_t)b * 64 + r) * Kin + k];
                if constexpr (AGG) v += S[b * Kin + k];
            }
            sH[r][cidx] = v;
            int k2 = kbase + r;
            int o = o0 + cidx;
            sW[r][cidx] = (k2 < Kin && o < Kout) ? W[(size_t)k2 * Kout + o] : 0.f;
        }
        __syncthreads();
        for (int kk = 0; kk < 64; ++kk) {
            float xn[4], wo[4];
            #pragma unroll
            for (int j = 0; j < 4; ++j) xn[j] = sH[nt + 16 * j][kk];
            #pragma unroll
            for (int i = 0; i < 4; ++i) wo[i] = sW[kk][og * 4 + i];
            #pragma unroll
            for (int i = 0; i < 4; ++i)
                #pragma unroll
                for (int j = 0; j < 4; ++j)
                    acc[i][j] = fmaf(wo[i], xn[j], acc[i][j]);
        }
        __syncthreads();
    }
    #pragma unroll
    for (int i = 0; i < 4; ++i) {
        int o = o0 + og * 4 + i;
        if (o < Kout) {
            float bb = Bb[o];
            #pragma unroll
            for (int j = 0; j < 4; ++j) {
                int n = nt + 16 * j;
                float v = acc[i][j] + bb;
                if constexpr (RELU) v = fmaxf(v, 0.f);
                Y[((size_t)b * 64 + n) * Kout + o] = v;
            }
        }
    }
}

// ---------------------------------------------------------------------------
// Fused 4-layer classifier head. One block per batch element (32 blocks).
// ---------------------------------------------------------------------------
__global__ __launch_bounds__(256) void classifier_k(
    const float* __restrict__ Hin,
    const float* __restrict__ w1, const float* __restrict__ b1,
    const float* __restrict__ w2, const float* __restrict__ b2,
    const float* __restrict__ w3, const float* __restrict__ b3,
    const float* __restrict__ w4, const float* __restrict__ b4,
    float* __restrict__ out)
{
    const int b = blockIdx.x, tid = threadIdx.x;
    __shared__ float sf[2240];
    __shared__ float s1[256];
    __shared__ float s2[64];
    __shared__ float s3[16];
    for (int i = tid; i < 2240; i += 256) sf[i] = Hin[(size_t)b * 2240 + i];
    __syncthreads();
    {
        float acc = b1[tid];
        for (int k = 0; k < 2240; ++k)
            acc = fmaf(sf[k], w1[(size_t)k * 256 + tid], acc);
        s1[tid] = elu_f(acc);
    }
    __syncthreads();
    if (tid < 64) {
        float acc = b2[tid];
        for (int k = 0; k < 256; ++k) acc = fmaf(s1[k], w2[k * 64 + tid], acc);
        s2[tid] = elu_f(acc);
    }
    __syncthreads();
    if (tid < 16) {
        float acc = b3[tid];
        for (int k = 0; k < 64; ++k) acc = fmaf(s2[k], w3[k * 16 + tid], acc);
        s3[tid] = elu_f(acc);
    }
    __syncthreads();
    if (tid < 2) {
        float acc = b4[tid];
        for (int k = 0; k < 16; ++k) acc = fmaf(s3[k], w4[k * 2 + tid], acc);
        out[b * 2 + tid] = acc;
    }
}

// ---------------------------------------------------------------------------
extern "C" void kernel_launch(void* const* d_in, const int* in_sizes, int n_in,
                              void* d_out, int out_size, void* d_ws, size_t ws_size,
                              hipStream_t stream)
{
    const float* x     = (const float*)d_in[0];
    const float* w1    = (const float*)d_in[1];
    const float* b1    = (const float*)d_in[2];
    const float* bn1_g = (const float*)d_in[3];
    const float* bn1_b = (const float*)d_in[4];
    const float* bn1_m = (const float*)d_in[5];
    const float* bn1_v = (const float*)d_in[6];
    const float* w2    = (const float*)d_in[7];
    const float* b2    = (const float*)d_in[8];
    const float* bn2_g = (const float*)d_in[9];
    const float* bn2_b = (const float*)d_in[10];
    const float* bn2_m = (const float*)d_in[11];
    const float* bn2_v = (const float*)d_in[12];
    const float* w3    = (const float*)d_in[13];
    const float* b3    = (const float*)d_in[14];
    const float* w4    = (const float*)d_in[15];
    const float* b4    = (const float*)d_in[16];
    const float* attn_w = (const float*)d_in[17];
    const float* attn_b = (const float*)d_in[18];
    const float* attn_u = (const float*)d_in[19];
    const float* g0_w1 = (const float*)d_in[20];
    const float* g0_b1 = (const float*)d_in[21];
    const float* g0_w2 = (const float*)d_in[22];
    const float* g0_b2 = (const float*)d_in[23];
    const float* g1_w1 = (const float*)d_in[24];
    const float* g1_b1 = (const float*)d_in[25];
    const float* g1_w2 = (const float*)d_in[26];
    const float* g1_b2 = (const float*)d_in[27];
    const float* g2_w1 = (const float*)d_in[28];
    const float* g2_b1 = (const float*)d_in[29];
    const float* g2_w2 = (const float*)d_in[30];
    const float* g2_b2 = (const float*)d_in[31];
    const float* c_w1  = (const float*)d_in[32];
    const float* c_b1  = (const float*)d_in[33];
    const float* c_w2  = (const float*)d_in[34];
    const float* c_b2  = (const float*)d_in[35];
    const float* c_w3  = (const float*)d_in[36];
    const float* c_b3  = (const float*)d_in[37];
    const float* c_w4  = (const float*)d_in[38];
    const float* c_b4  = (const float*)d_in[39];
    float* out = (float*)d_out;

    // Workspace layout (floats). Peak live set: h1 (R1) + h2 (R2) = 36.6 MB.
    float* R1 = (float*)d_ws;          // 6,291,456 floats
    float* R2 = R1 + 6291456;          // 2,850,816 floats
    float* h1 = R1;                    // [512,64,192]
    float* h2 = R2;                    // [512,64,87]
    float* h3 = R1;                    // [512,64,82]   (h1 dead)
    float* p4 = R2;                    // [512,64,40]   (h2 dead)
    float* h4 = R1;                    // [512,64,35]   (h3 dead)
    float* ha = R2;                    // [32,64,35]    (p4 dead)
    float* S  = R2 + 131072;           // [32,256]
    float* T  = R1;                    // [32,64,256]   (h4 dead)
    float* Hn = R1 + 524288;           // [32,64,256]
    float* H3 = R1 + 1048576;          // [32,64,35]

    dim3 blk(256);
    // CNN stack
    conv_elu_bn<20, 2, 1, true><<<dim3(512, 3), blk, 0, stream>>>(
        x, w1, b1, bn1_g, bn1_b, bn1_m, bn1_v, h1, 400, 192);
    conv_elu_bn<20, 2, 0, true><<<dim3(512, 2), blk, 0, stream>>>(
        h1, w2, b2, bn2_g, bn2_b, bn2_m, bn2_v, h2, 192, 87);
    conv_elu_bn<6, 1, 0, false><<<dim3(512, 2), blk, 0, stream>>>(
        h2, w3, b3, nullptr, nullptr, nullptr, nullptr, h3, 87, 82);
    pool3_k<<<dim3(5120), blk, 0, stream>>>(h3, p4);
    conv_elu_bn<6, 1, 0, false><<<dim3(512, 1), blk, 0, stream>>>(
        p4, w4, b4, nullptr, nullptr, nullptr, nullptr, h4, 40, 35);
    // Attention pooling over crops
    attn_pool_k<<<dim3(2048), blk, 0, stream>>>(h4, attn_w, attn_b, attn_u, ha);
    // GIN layer 0
    colsum_k<<<dim3(32, 1), blk, 0, stream>>>(ha, S, 35);
    gin_gemm<true,  true ><<<dim3(32, 4), blk, 0, stream>>>(ha, S, g0_w1, g0_b1, T, 35, 256);
    gin_gemm<false, true ><<<dim3(32, 4), blk, 0, stream>>>(T, nullptr, g0_w2, g0_b2, Hn, 256, 256);
    // GIN layer 1
    colsum_k<<<dim3(32, 1), blk, 0, stream>>>(Hn, S, 256);
    gin_gemm<true,  true ><<<dim3(32, 4), blk, 0, stream>>>(Hn, S, g1_w1, g1_b1, T, 256, 256);
    gin_gemm<false, true ><<<dim3(32, 4), blk, 0, stream>>>(T, nullptr, g1_w2, g1_b2, Hn, 256, 256);
    // GIN layer 2 (no activation after second matmul)
    colsum_k<<<dim3(32, 1), blk, 0, stream>>>(Hn, S, 256);
    gin_gemm<true,  true ><<<dim3(32, 1), blk, 0, stream>>>(Hn, S, g2_w1, g2_b1, T, 256, 35);
    gin_gemm<false, false><<<dim3(32, 1), blk, 0, stream>>>(T, nullptr, g2_w2, g2_b2, H3, 35, 35);
    // Classifier
    classifier_k<<<dim3(32), blk, 0, stream>>>(
        H3, c_w1, c_b1, c_w2, c_b2, c_w3, c_b3, c_w4, c_b4, out);
}

// Round 2
// 589.880 us; speedup vs baseline: 1.7040x; 1.7040x over previous
//
#include <hip/hip_runtime.h>
#include <math.h>

typedef __attribute__((ext_vector_type(8))) __bf16 bf16x8;
typedef __attribute__((ext_vector_type(4))) float f32x4;

__device__ __forceinline__ float elu_f(float v) {
    return v > 0.f ? v : (expf(v) - 1.f);
}

// ---------------------------------------------------------------------------
// Weight reorder: w[co][ci][K] fp32 -> wT[k][co][ci] bf16, all four convs.
// ---------------------------------------------------------------------------
__global__ __launch_bounds__(256) void prep_weights(
    const float* __restrict__ w1, const float* __restrict__ w2,
    const float* __restrict__ w3, const float* __restrict__ w4,
    __bf16* __restrict__ t1, __bf16* __restrict__ t2,
    __bf16* __restrict__ t3, __bf16* __restrict__ t4)
{
    int idx = blockIdx.x * 256 + threadIdx.x;
    if (idx < 81920) {
        int k = idx / 4096, r = idx - k * 4096, co = r >> 6, ci = r & 63;
        t1[idx] = (__bf16)w1[(co * 64 + ci) * 20 + k];
    } else if (idx < 163840) {
        int j = idx - 81920;
        int k = j / 4096, r = j - k * 4096, co = r >> 6, ci = r & 63;
        t2[j] = (__bf16)w2[(co * 64 + ci) * 20 + k];
    } else if (idx < 188416) {
        int j = idx - 163840;
        int k = j / 4096, r = j - k * 4096, co = r >> 6, ci = r & 63;
        t3[j] = (__bf16)w3[(co * 64 + ci) * 6 + k];
    } else if (idx < 212992) {
        int j = idx - 188416;
        int k = j / 4096, r = j - k * 4096, co = r >> 6, ci = r & 63;
        t4[j] = (__bf16)w4[(co * 64 + ci) * 6 + k];
    }
}

// ---------------------------------------------------------------------------
// MFMA conv1d, Cin=Cout=64. Output layout [n][t][64co] bf16.
// Wave tile: 48t x 64co (3x4 fragments of 16x16x32 bf16).
// LDS input layout [pos][ci] bf16, even/odd-position split for stride 2 so
// A-fragment reads hit consecutive rows (stride 72 bf16 = 144B: aligned b128,
// 2-way bank conflicts only).
// IMODE: 0 = fp32 [ci][L] input (transpose), 1 = bf16 [t][64] copy,
//        2 = bf16 [t][64] with fused avgpool3/s2 from raw length 82.
// ---------------------------------------------------------------------------
template<int K, int STRIDE, int PAD, bool DO_BN, int IMODE,
         int NPB, int TPN, int LIN, int LOUT>
__global__ __launch_bounds__(256, 2) void conv_mfma(
    const void* __restrict__ xin, const __bf16* __restrict__ wT,
    const float* __restrict__ bias,
    const float* __restrict__ bn_g, const float* __restrict__ bn_b,
    const float* __restrict__ bn_m, const float* __restrict__ bn_v,
    __bf16* __restrict__ y)
{
    constexpr int TBLK  = TPN * 48;
    constexpr int VSPAN = STRIDE * (TBLK - 1) + K;
    constexpr int NBUF  = (STRIDE == 2) ? 2 : 1;
    constexpr int ROWS  = (VSPAN + NBUF - 1) / NBUF;
    __shared__ __align__(16) __bf16 sx[NPB * NBUF * ROWS * 72];
    __shared__ __align__(16) __bf16 sw[2 * 64 * 72];

    const int tid = threadIdx.x;
    const int nb  = blockIdx.x * NPB;

    // ---- stage input span into LDS as [pos-split][ci] bf16 ----
    if constexpr (IMODE == 0) {
        const float* xg = (const float*)xin + (size_t)nb * 64 * LIN;
        for (int idx = tid; idx < 64 * VSPAN; idx += 256) {
            int ci = idx / VSPAN, v = idx - ci * VSPAN;
            int pos = v - PAD;
            float val = (pos >= 0 && pos < LIN) ? xg[ci * LIN + pos] : 0.f;
            sx[((v & (NBUF - 1)) * ROWS + (v >> (NBUF - 1))) * 72 + ci] = (__bf16)val;
        }
    } else {
        const __bf16* xg = (const __bf16*)xin;
        for (int idx = tid; idx < NPB * VSPAN * 8; idx += 256) {
            int n_l = idx / (VSPAN * 8);
            int r   = idx - n_l * (VSPAN * 8);
            int v = r >> 3, c8 = (r & 7) * 8;
            int buf = (STRIDE == 2) ? (v & 1) : 0;
            int row = (STRIDE == 2) ? (v >> 1) : v;
            __bf16* dst = sx + ((size_t)(n_l * NBUF + buf) * ROWS + row) * 72 + c8;
            if constexpr (IMODE == 1) {
                if (v < LIN) {
                    const __bf16* src = xg + (((size_t)(nb + n_l) * LIN + v) * 64 + c8);
                    *(uint4*)dst = *(const uint4*)src;
                } else {
                    #pragma unroll
                    for (int e = 0; e < 8; ++e) dst[e] = (__bf16)0.f;
                }
            } else {
                if (v < LIN) {
                    const __bf16* s0 = xg + (((size_t)(nb + n_l) * 82 + 2 * v) * 64 + c8);
                    #pragma unroll
                    for (int e = 0; e < 8; ++e)
                        dst[e] = (__bf16)(((float)s0[e] + (float)s0[64 + e] +
                                           (float)s0[128 + e]) * (1.f / 3.f));
                } else {
                    #pragma unroll
                    for (int e = 0; e < 8; ++e) dst[e] = (__bf16)0.f;
                }
            }
        }
    }
    __syncthreads();

    const int wave = tid >> 6, lane = tid & 63;
    const int n_l  = wave / TPN, tile = wave - n_l * TPN;
    const int m    = lane & 15, quad = lane >> 4;
    const __bf16* sxn = sx + (size_t)n_l * NBUF * ROWS * 72;

    f32x4 acc[3][4];
    #pragma unroll
    for (int mi = 0; mi < 3; ++mi)
        #pragma unroll
        for (int nj = 0; nj < 4; ++nj)
            acc[mi][nj] = (f32x4){0.f, 0.f, 0.f, 0.f};

    for (int kp = 0; kp < K; kp += 2) {
        // stage two taps of weights: sw[tap][co][ci] (row stride 72)
        for (int i = tid; i < 1024; i += 256) {
            int tap = i >> 9, c = i & 511;
            int co = c >> 3, c8 = (c & 7) * 8;
            *(uint4*)(sw + (size_t)(tap * 64 + co) * 72 + c8) =
                *(const uint4*)(wT + ((size_t)(kp + tap) * 64 + co) * 64 + c8);
        }
        __syncthreads();
        #pragma unroll
        for (int dt = 0; dt < 2; ++dt) {
            const int k = kp + dt;
            const int buf    = (STRIDE == 2) ? (k & 1) : 0;
            const int rowoff = (STRIDE == 2) ? (k >> 1) : k;
            const __bf16* abase = sxn + ((size_t)buf * ROWS + tile * 48 + m + rowoff) * 72;
            const __bf16* bbase = sw + (size_t)dt * 64 * 72 + m * 72;
            #pragma unroll
            for (int s = 0; s < 2; ++s) {
                bf16x8 af[3], bfr[4];
                #pragma unroll
                for (int mi = 0; mi < 3; ++mi)
                    af[mi] = *(const bf16x8*)(abase + mi * (16 * 72) + s * 32 + quad * 8);
                #pragma unroll
                for (int nj = 0; nj < 4; ++nj)
                    bfr[nj] = *(const bf16x8*)(bbase + nj * (16 * 72) + s * 32 + quad * 8);
                #pragma unroll
                for (int mi = 0; mi < 3; ++mi)
                    #pragma unroll
                    for (int nj = 0; nj < 4; ++nj)
                        acc[mi][nj] = __builtin_amdgcn_mfma_f32_16x16x32_bf16(
                            af[mi], bfr[nj], acc[mi][nj], 0, 0, 0);
            }
        }
        __syncthreads();
    }

    // epilogue: bias -> ELU -> (BN) -> bf16 store, [n][t][co]
    #pragma unroll
    for (int nj = 0; nj < 4; ++nj) {
        const int co = nj * 16 + m;
        const float bi = bias[co];
        float scale = 1.f, shift = 0.f;
        if constexpr (DO_BN) {
            float inv = bn_g[co] / sqrtf(bn_v[co] + 1e-5f);
            scale = inv; shift = bn_b[co] - bn_m[co] * inv;
        }
        #pragma unroll
        for (int mi = 0; mi < 3; ++mi) {
            #pragma unroll
            for (int r = 0; r < 4; ++r) {
                int t = tile * 48 + mi * 16 + quad * 4 + r;
                if (t < LOUT) {
                    float v = acc[mi][nj][r] + bi;
                    v = elu_f(v);
                    if constexpr (DO_BN) v = v * scale + shift;
                    y[((size_t)(nb + n_l) * LOUT + t) * 64 + co] = (__bf16)v;
                }
            }
        }
    }
}

// ---------------------------------------------------------------------------
// Attention pooling over crop dim. One block per (b,c). h: [512][35][64] bf16.
// ---------------------------------------------------------------------------
__global__ __launch_bounds__(256) void attn_pool_k(
    const __bf16* __restrict__ h, const float* __restrict__ W,
    const float* __restrict__ ab, const float* __restrict__ u,
    float* __restrict__ out)
{
    const int b = blockIdx.x >> 6;
    const int c = blockIdx.x & 63;
    __shared__ float sh[16 * 35];
    __shared__ float slog[16];
    __shared__ float sred[4];
    __shared__ float salpha[16];
    const int tid = threadIdx.x;
    for (int idx = tid; idx < 16 * 35; idx += 256) {
        int s = idx / 35, hh = idx - s * 35;
        sh[idx] = (float)h[((size_t)(b * 16 + s) * 35 + hh) * 64 + c];
    }
    __syncthreads();
    float Wc[35];
    #pragma unroll
    for (int k = 0; k < 35; ++k) Wc[k] = W[k * 256 + tid];
    const float myb = ab[tid], myu = u[tid];
    for (int s = 0; s < 16; ++s) {
        float dot = myb;
        #pragma unroll
        for (int k = 0; k < 35; ++k) dot = fmaf(sh[s * 35 + k], Wc[k], dot);
        float val = tanhf(dot) * myu;
        #pragma unroll
        for (int off = 32; off > 0; off >>= 1) val += __shfl_down(val, off, 64);
        if ((tid & 63) == 0) sred[tid >> 6] = val;
        __syncthreads();
        if (tid == 0) slog[s] = sred[0] + sred[1] + sred[2] + sred[3];
        __syncthreads();
    }
    if (tid == 0) {
        float mx = slog[0];
        for (int s = 1; s < 16; ++s) mx = fmaxf(mx, slog[s]);
        float sum = 0.f, e[16];
        for (int s = 0; s < 16; ++s) { e[s] = expf(slog[s] - mx); sum += e[s]; }
        float inv = 1.f / sum;
        for (int s = 0; s < 16; ++s) salpha[s] = e[s] * inv;
    }
    __syncthreads();
    if (tid < 35) {
        float acc = 0.f;
        for (int s = 0; s < 16; ++s) acc = fmaf(sh[s * 35 + tid], salpha[s], acc);
        out[((size_t)(b * 64 + c)) * 35 + tid] = elu_f(acc);
    }
}

// ---------------------------------------------------------------------------
// Column sum over the 64 graph nodes: S[b,k] = sum_n H[b,n,k]
// ---------------------------------------------------------------------------
__global__ __launch_bounds__(256) void colsum_k(const float* __restrict__ H,
                                                float* __restrict__ S, int Kd)
{
    int b = blockIdx.x;
    int k = blockIdx.y * 256 + threadIdx.x;
    if (k >= Kd) return;
    const float* Hb = H + (size_t)b * 64 * Kd + k;
    float s = 0.f;
    for (int n = 0; n < 64; ++n) s += Hb[(size_t)n * Kd];
    S[b * Kd + k] = s;
}

// ---------------------------------------------------------------------------
// GIN matmul: Y[b,n,o] = act( sum_k (H[b,n,k] (+S[b,k])) * W[k,o] + B[o] )
// ---------------------------------------------------------------------------
template<bool AGG, bool RELU>
__global__ __launch_bounds__(256) void gin_gemm(
    const float* __restrict__ H, const float* __restrict__ S,
    const float* __restrict__ W, const float* __restrict__ Bb,
    float* __restrict__ Y, int Kin, int Kout)
{
    const int b  = blockIdx.x;
    const int o0 = blockIdx.y * 64;
    __shared__ float sH[64][68];
    __shared__ float sW[64][68];
    const int tid = threadIdx.x;
    const int nt = tid & 15;
    const int og = tid >> 4;
    float acc[4][4] = {};
    const int nch = (Kin + 63) >> 6;
    for (int kc = 0; kc < nch; ++kc) {
        const int kbase = kc * 64;
        for (int idx = tid; idx < 4096; idx += 256) {
            int r = idx >> 6, cidx = idx & 63;
            int k = kbase + cidx;
            float v = 0.f;
            if (k < Kin) {
                v = H[((size_t)b * 64 + r) * Kin + k];
                if constexpr (AGG) v += S[b * Kin + k];
            }
            sH[r][cidx] = v;
            int k2 = kbase + r;
            int o = o0 + cidx;
            sW[r][cidx] = (k2 < Kin && o < Kout) ? W[(size_t)k2 * Kout + o] : 0.f;
        }
        __syncthreads();
        for (int kk = 0; kk < 64; ++kk) {
            float xn[4], wo[4];
            #pragma unroll
            for (int j = 0; j < 4; ++j) xn[j] = sH[nt + 16 * j][kk];
            #pragma unroll
            for (int i = 0; i < 4; ++i) wo[i] = sW[kk][og * 4 + i];
            #pragma unroll
            for (int i = 0; i < 4; ++i)
                #pragma unroll
                for (int j = 0; j < 4; ++j)
                    acc[i][j] = fmaf(wo[i], xn[j], acc[i][j]);
        }
        __syncthreads();
    }
    #pragma unroll
    for (int i = 0; i < 4; ++i) {
        int o = o0 + og * 4 + i;
        if (o < Kout) {
            float bb = Bb[o];
            #pragma unroll
            for (int j = 0; j < 4; ++j) {
                int n = nt + 16 * j;
                float v = acc[i][j] + bb;
                if constexpr (RELU) v = fmaxf(v, 0.f);
                Y[((size_t)b * 64 + n) * Kout + o] = v;
            }
        }
    }
}

// ---------------------------------------------------------------------------
// Fused 4-layer classifier head. One block per batch element (32 blocks).
// ---------------------------------------------------------------------------
__global__ __launch_bounds__(256) void classifier_k(
    const float* __restrict__ Hin,
    const float* __restrict__ w1, const float* __restrict__ b1,
    const float* __restrict__ w2, const float* __restrict__ b2,
    const float* __restrict__ w3, const float* __restrict__ b3,
    const float* __restrict__ w4, const float* __restrict__ b4,
    float* __restrict__ out)
{
    const int b = blockIdx.x, tid = threadIdx.x;
    __shared__ float sf[2240];
    __shared__ float s1[256];
    __shared__ float s2[64];
    __shared__ float s3[16];
    for (int i = tid; i < 2240; i += 256) sf[i] = Hin[(size_t)b * 2240 + i];
    __syncthreads();
    {
        float acc = b1[tid];
        for (int k = 0; k < 2240; ++k)
            acc = fmaf(sf[k], w1[(size_t)k * 256 + tid], acc);
        s1[tid] = elu_f(acc);
    }
    __syncthreads();
    if (tid < 64) {
        float acc = b2[tid];
        for (int k = 0; k < 256; ++k) acc = fmaf(s1[k], w2[k * 64 + tid], acc);
        s2[tid] = elu_f(acc);
    }
    __syncthreads();
    if (tid < 16) {
        float acc = b3[tid];
        for (int k = 0; k < 64; ++k) acc = fmaf(s2[k], w3[k * 16 + tid], acc);
        s3[tid] = elu_f(acc);
    }
    __syncthreads();
    if (tid < 2) {
        float acc = b4[tid];
        for (int k = 0; k < 16; ++k) acc = fmaf(s3[k], w4[k * 2 + tid], acc);
        out[b * 2 + tid] = acc;
    }
}

// ---------------------------------------------------------------------------
extern "C" void kernel_launch(void* const* d_in, const int* in_sizes, int n_in,
                              void* d_out, int out_size, void* d_ws, size_t ws_size,
                              hipStream_t stream)
{
    const float* x     = (const float*)d_in[0];
    const float* w1    = (const float*)d_in[1];
    const float* b1    = (const float*)d_in[2];
    const float* bn1_g = (const float*)d_in[3];
    const float* bn1_b = (const float*)d_in[4];
    const float* bn1_m = (const float*)d_in[5];
    const float* bn1_v = (const float*)d_in[6];
    const float* w2    = (const float*)d_in[7];
    const float* b2    = (const float*)d_in[8];
    const float* bn2_g = (const float*)d_in[9];
    const float* bn2_b = (const float*)d_in[10];
    const float* bn2_m = (const float*)d_in[11];
    const float* bn2_v = (const float*)d_in[12];
    const float* w3    = (const float*)d_in[13];
    const float* b3    = (const float*)d_in[14];
    const float* w4    = (const float*)d_in[15];
    const float* b4    = (const float*)d_in[16];
    const float* attn_w = (const float*)d_in[17];
    const float* attn_b = (const float*)d_in[18];
    const float* attn_u = (const float*)d_in[19];
    const float* g0_w1 = (const float*)d_in[20];
    const float* g0_b1 = (const float*)d_in[21];
    const float* g0_w2 = (const float*)d_in[22];
    const float* g0_b2 = (const float*)d_in[23];
    const float* g1_w1 = (const float*)d_in[24];
    const float* g1_b1 = (const float*)d_in[25];
    const float* g1_w2 = (const float*)d_in[26];
    const float* g1_b2 = (const float*)d_in[27];
    const float* g2_w1 = (const float*)d_in[28];
    const float* g2_b1 = (const float*)d_in[29];
    const float* g2_w2 = (const float*)d_in[30];
    const float* g2_b2 = (const float*)d_in[31];
    const float* c_w1  = (const float*)d_in[32];
    const float* c_b1  = (const float*)d_in[33];
    const float* c_w2  = (const float*)d_in[34];
    const float* c_b2  = (const float*)d_in[35];
    const float* c_w3  = (const float*)d_in[36];
    const float* c_b3  = (const float*)d_in[37];
    const float* c_w4  = (const float*)d_in[38];
    const float* c_b4  = (const float*)d_in[39];
    float* out = (float*)d_out;

    // Workspace layout (byte offsets, all 256-aligned)
    char* ws = (char*)d_ws;
    __bf16* wT1 = (__bf16*)(ws + 0);          // 20*64*64  -> 163840 B
    __bf16* wT2 = (__bf16*)(ws + 163840);     // 163840 B
    __bf16* wT3 = (__bf16*)(ws + 327680);     // 6*64*64   -> 49152 B
    __bf16* wT4 = (__bf16*)(ws + 376832);     // 49152 B
    __bf16* h1  = (__bf16*)(ws + 425984);     // 512*192*64 bf16 = 12582912 B
    __bf16* h2  = (__bf16*)(ws + 13008896);   // 512*87*64  bf16 = 5701632 B
    __bf16* h3  = (__bf16*)(ws + 18710528);   // 512*82*64  bf16 = 5373952 B
    __bf16* h4  = (__bf16*)(ws + 24084480);   // 512*35*64  bf16 = 2293760 B
    float*  ha  = (float*)(ws + 26378240);    // 32*64*35 f32 = 286720 B
    float*  S   = (float*)(ws + 26664960);    // 32*256 f32 = 32768 B
    float*  T   = (float*)(ws + 26697728);    // 32*64*256 f32 = 2097152 B
    float*  Hn  = (float*)(ws + 28794880);    // 2097152 B
    float*  H3  = (float*)(ws + 30892032);    // 286720 B

    dim3 blk(256);
    prep_weights<<<dim3(832), blk, 0, stream>>>(w1, w2, w3, w4, wT1, wT2, wT3, wT4);

    // CNN stack (bf16 MFMA), outputs in [n][t][64c] bf16
    conv_mfma<20, 2, 1, true, 0, 1, 4, 400, 192><<<dim3(512), blk, 0, stream>>>(
        x, wT1, b1, bn1_g, bn1_b, bn1_m, bn1_v, h1);
    conv_mfma<20, 2, 0, true, 1, 2, 2, 192, 87><<<dim3(256), blk, 0, stream>>>(
        h1, wT2, b2, bn2_g, bn2_b, bn2_m, bn2_v, h2);
    conv_mfma<6, 1, 0, false, 1, 2, 2, 87, 82><<<dim3(256), blk, 0, stream>>>(
        h2, wT3, b3, nullptr, nullptr, nullptr, nullptr, h3);
    conv_mfma<6, 1, 0, false, 2, 4, 1, 40, 35><<<dim3(128), blk, 0, stream>>>(
        h3, wT4, b4, nullptr, nullptr, nullptr, nullptr, h4);   // pool fused

    // Attention pooling over crops
    attn_pool_k<<<dim3(2048), blk, 0, stream>>>(h4, attn_w, attn_b, attn_u, ha);
    // GIN layer 0
    colsum_k<<<dim3(32, 1), blk, 0, stream>>>(ha, S, 35);
    gin_gemm<true,  true ><<<dim3(32, 4), blk, 0, stream>>>(ha, S, g0_w1, g0_b1, T, 35, 256);
    gin_gemm<false, true ><<<dim3(32, 4), blk, 0, stream>>>(T, nullptr, g0_w2, g0_b2, Hn, 256, 256);
    // GIN layer 1
    colsum_k<<<dim3(32, 1), blk, 0, stream>>>(Hn, S, 256);
    gin_gemm<true,  true ><<<dim3(32, 4), blk, 0, stream>>>(Hn, S, g1_w1, g1_b1, T, 256, 256);
    gin_gemm<false, true ><<<dim3(32, 4), blk, 0, stream>>>(T, nullptr, g1_w2, g1_b2, Hn, 256, 256);
    // GIN layer 2 (no activation after second matmul)
    colsum_k<<<dim3(32, 1), blk, 0, stream>>>(Hn, S, 256);
    gin_gemm<true,  true ><<<dim3(32, 1), blk, 0, stream>>>(Hn, S, g2_w1, g2_b1, T, 256, 35);
    gin_gemm<false, false><<<dim3(32, 1), blk, 0, stream>>>(T, nullptr, g2_w2, g2_b2, H3, 35, 35);
    // Classifier
    classifier_k<<<dim3(32), blk, 0, stream>>>(
        H3, c_w1, c_b1, c_w2, c_b2, c_w3, c_b3, c_w4, c_b4, out);
}

// Round 4
// 524.701 us; speedup vs baseline: 1.9156x; 1.1242x over previous
//
#include <hip/hip_runtime.h>
#include <math.h>

typedef __attribute__((ext_vector_type(8))) __bf16 bf16x8;
typedef __attribute__((ext_vector_type(4))) float f32x4;

__device__ __forceinline__ float elu_f(float v) {
    return v > 0.f ? v : (expf(v) - 1.f);
}

// ---------------------------------------------------------------------------
// Conv weight reorder: w[co][ci][K] fp32 -> wT[k][co][ci] bf16 (all 4 convs).
// ---------------------------------------------------------------------------
__global__ __launch_bounds__(256) void prep_weights(
    const float* __restrict__ w1, const float* __restrict__ w2,
    const float* __restrict__ w3, const float* __restrict__ w4,
    __bf16* __restrict__ t1, __bf16* __restrict__ t2,
    __bf16* __restrict__ t3, __bf16* __restrict__ t4)
{
    int idx = blockIdx.x * 256 + threadIdx.x;
    if (idx < 81920) {
        int k = idx / 4096, r = idx - k * 4096, co = r >> 6, ci = r & 63;
        t1[idx] = (__bf16)w1[(co * 64 + ci) * 20 + k];
    } else if (idx < 163840) {
        int j = idx - 81920;
        int k = j / 4096, r = j - k * 4096, co = r >> 6, ci = r & 63;
        t2[j] = (__bf16)w2[(co * 64 + ci) * 20 + k];
    } else if (idx < 188416) {
        int j = idx - 163840;
        int k = j / 4096, r = j - k * 4096, co = r >> 6, ci = r & 63;
        t3[j] = (__bf16)w3[(co * 64 + ci) * 6 + k];
    } else if (idx < 212992) {
        int j = idx - 188416;
        int k = j / 4096, r = j - k * 4096, co = r >> 6, ci = r & 63;
        t4[j] = (__bf16)w4[(co * 64 + ci) * 6 + k];
    }
}

// ---------------------------------------------------------------------------
// Tiled transpose+convert with hi/lo split: src fp32 [K][O] ->
// dst bf16 [Opad][Kpad] hi plane at 0, lo plane at Opad*Kpad (zero pad).
// For GIN weights + classifier w1. 197 blocks.
// ---------------------------------------------------------------------------
__global__ __launch_bounds__(256) void prep_tr(
    const float* __restrict__ g0w1, const float* __restrict__ g0w2,
    const float* __restrict__ g1w1, const float* __restrict__ g1w2,
    const float* __restrict__ g2w1, const float* __restrict__ g2w2,
    const float* __restrict__ cw1,
    __bf16* __restrict__ d0, __bf16* __restrict__ d1, __bf16* __restrict__ d2,
    __bf16* __restrict__ d3, __bf16* __restrict__ d4, __bf16* __restrict__ d5,
    __bf16* __restrict__ d6)
{
    int bid = blockIdx.x;
    const float* src; __bf16* dst; int K, O, Kpad, Opad, tile;
    if (bid < 4)       { src = g0w1; dst = d0; K = 35;   O = 256; Kpad = 64;   Opad = 256; tile = bid; }
    else if (bid < 20) { src = g0w2; dst = d1; K = 256;  O = 256; Kpad = 256;  Opad = 256; tile = bid - 4; }
    else if (bid < 36) { src = g1w1; dst = d2; K = 256;  O = 256; Kpad = 256;  Opad = 256; tile = bid - 20; }
    else if (bid < 52) { src = g1w2; dst = d3; K = 256;  O = 256; Kpad = 256;  Opad = 256; tile = bid - 36; }
    else if (bid < 56) { src = g2w1; dst = d4; K = 256;  O = 35;  Kpad = 256;  Opad = 64;  tile = bid - 52; }
    else if (bid < 57) { src = g2w2; dst = d5; K = 35;   O = 35;  Kpad = 64;   Opad = 64;  tile = 0; }
    else               { src = cw1;  dst = d6; K = 2240; O = 256; Kpad = 2240; Opad = 256; tile = bid - 57; }
    int ktiles = Kpad >> 6;
    int ot = tile / ktiles, kt = tile - ot * ktiles;
    int k0 = kt * 64, o0 = ot * 64;
    size_t LOFF = (size_t)Opad * Kpad;
    __shared__ float tl[64][68];
    int c = threadIdx.x & 63, rr = threadIdx.x >> 6;
    #pragma unroll
    for (int it = 0; it < 16; ++it) {
        int r = rr + it * 4;
        int kk = k0 + r, oo = o0 + c;
        tl[r][c] = (kk < K && oo < O) ? src[(size_t)kk * O + oo] : 0.f;
    }
    __syncthreads();
    #pragma unroll
    for (int it = 0; it < 16; ++it) {
        int r = rr + it * 4;
        float v = tl[c][r];
        __bf16 hi = (__bf16)v;
        float lo = v - (float)hi;
        size_t pos = (size_t)(o0 + r) * Kpad + k0 + c;
        dst[pos] = hi;
        dst[LOFF + pos] = (__bf16)lo;
    }
}

// ---------------------------------------------------------------------------
// MFMA conv1d, Cin=Cout=64. Output [n][t][64co] bf16.
// Input staged to LDS ONCE; weights B-fragments direct from global wT
// (L2-hot) -> zero barriers in the K loop.
// ---------------------------------------------------------------------------
template<int K, int STRIDE, int PAD, bool DO_BN, int IMODE,
         int NPB, int TPN, int LIN, int LOUT>
__global__ __launch_bounds__(NPB * TPN * 64, 2) void conv_mfma(
    const void* __restrict__ xin, const __bf16* __restrict__ wT,
    const float* __restrict__ bias,
    const float* __restrict__ bn_g, const float* __restrict__ bn_b,
    const float* __restrict__ bn_m, const float* __restrict__ bn_v,
    __bf16* __restrict__ y)
{
    constexpr int THREADS = NPB * TPN * 64;
    constexpr int TBLK  = TPN * 48;
    constexpr int VSPAN = STRIDE * (TBLK - 1) + K;
    constexpr int NBUF  = (STRIDE == 2) ? 2 : 1;
    constexpr int ROWS  = (VSPAN + NBUF - 1) / NBUF;
    __shared__ __align__(16) __bf16 sx[NPB * NBUF * ROWS * 72];

    const int tid = threadIdx.x;
    const int nb  = blockIdx.x * NPB;

    if constexpr (IMODE == 0) {
        const float* xg = (const float*)xin + (size_t)nb * 64 * LIN;
        for (int idx = tid; idx < 64 * VSPAN; idx += THREADS) {
            int ci = idx / VSPAN, v = idx - ci * VSPAN;
            int pos = v - PAD;
            float val = (pos >= 0 && pos < LIN) ? xg[ci * LIN + pos] : 0.f;
            sx[((v & (NBUF - 1)) * ROWS + (v >> (NBUF - 1))) * 72 + ci] = (__bf16)val;
        }
    } else {
        const __bf16* xg = (const __bf16*)xin;
        for (int idx = tid; idx < NPB * VSPAN * 8; idx += THREADS) {
            int n_l = idx / (VSPAN * 8);
            int r   = idx - n_l * (VSPAN * 8);
            int v = r >> 3, c8 = (r & 7) * 8;
            int buf = (STRIDE == 2) ? (v & 1) : 0;
            int row = (STRIDE == 2) ? (v >> 1) : v;
            __bf16* dst = sx + ((size_t)(n_l * NBUF + buf) * ROWS + row) * 72 + c8;
            if constexpr (IMODE == 1) {
                if (v < LIN) {
                    const __bf16* src = xg + (((size_t)(nb + n_l) * LIN + v) * 64 + c8);
                    *(uint4*)dst = *(const uint4*)src;
                } else {
                    #pragma unroll
                    for (int e = 0; e < 8; ++e) dst[e] = (__bf16)0.f;
                }
            } else {
                if (v < LIN) {
                    const __bf16* s0 = xg + (((size_t)(nb + n_l) * 82 + 2 * v) * 64 + c8);
                    #pragma unroll
                    for (int e = 0; e < 8; ++e)
                        dst[e] = (__bf16)(((float)s0[e] + (float)s0[64 + e] +
                                           (float)s0[128 + e]) * (1.f / 3.f));
                } else {
                    #pragma unroll
                    for (int e = 0; e < 8; ++e) dst[e] = (__bf16)0.f;
                }
            }
        }
    }
    __syncthreads();

    const int wave = tid >> 6, lane = tid & 63;
    const int n_l  = wave / TPN, tile = wave - n_l * TPN;
    const int m    = lane & 15, quad = lane >> 4;
    const __bf16* sxn = sx + (size_t)n_l * NBUF * ROWS * 72;

    f32x4 acc[3][4];
    #pragma unroll
    for (int mi = 0; mi < 3; ++mi)
        #pragma unroll
        for (int nj = 0; nj < 4; ++nj)
            acc[mi][nj] = (f32x4){0.f, 0.f, 0.f, 0.f};

    #pragma unroll 2
    for (int kp = 0; kp < K; ++kp) {
        const int buf    = (STRIDE == 2) ? (kp & 1) : 0;
        const int rowoff = (STRIDE == 2) ? (kp >> 1) : kp;
        const __bf16* abase = sxn + ((size_t)buf * ROWS + tile * 48 + m + rowoff) * 72;
        const __bf16* wbase = wT + (size_t)kp * 4096 + m * 64;
        #pragma unroll
        for (int s = 0; s < 2; ++s) {
            bf16x8 af[3], bfr[4];
            #pragma unroll
            for (int mi = 0; mi < 3; ++mi)
                af[mi] = *(const bf16x8*)(abase + mi * (16 * 72) + s * 32 + quad * 8);
            #pragma unroll
            for (int nj = 0; nj < 4; ++nj)
                bfr[nj] = *(const bf16x8*)(wbase + nj * 1024 + s * 32 + quad * 8);
            #pragma unroll
            for (int mi = 0; mi < 3; ++mi)
                #pragma unroll
                for (int nj = 0; nj < 4; ++nj)
                    acc[mi][nj] = __builtin_amdgcn_mfma_f32_16x16x32_bf16(
                        af[mi], bfr[nj], acc[mi][nj], 0, 0, 0);
        }
    }

    #pragma unroll
    for (int nj = 0; nj < 4; ++nj) {
        const int co = nj * 16 + m;
        const float bi = bias[co];
        float scale = 1.f, shift = 0.f;
        if constexpr (DO_BN) {
            float inv = bn_g[co] / sqrtf(bn_v[co] + 1e-5f);
            scale = inv; shift = bn_b[co] - bn_m[co] * inv;
        }
        #pragma unroll
        for (int mi = 0; mi < 3; ++mi) {
            #pragma unroll
            for (int r = 0; r < 4; ++r) {
                int t = tile * 48 + mi * 16 + quad * 4 + r;
                if (t < LOUT) {
                    float v = acc[mi][nj][r] + bi;
                    v = elu_f(v);
                    if constexpr (DO_BN) v = v * scale + shift;
                    y[((size_t)(nb + n_l) * LOUT + t) * 64 + co] = (__bf16)v;
                }
            }
        }
    }
}

// ---------------------------------------------------------------------------
// Attention pooling over crop dim. One block per (b,c). h: [512][35][64] bf16.
// ---------------------------------------------------------------------------
__global__ __launch_bounds__(256) void attn_pool_k(
    const __bf16* __restrict__ h, const float* __restrict__ W,
    const float* __restrict__ ab, const float* __restrict__ u,
    float* __restrict__ out)
{
    const int b = blockIdx.x >> 6;
    const int c = blockIdx.x & 63;
    __shared__ float sh[16 * 35];
    __shared__ float slog[16];
    __shared__ float sred[4];
    __shared__ float salpha[16];
    const int tid = threadIdx.x;
    for (int idx = tid; idx < 16 * 35; idx += 256) {
        int s = idx / 35, hh = idx - s * 35;
        sh[idx] = (float)h[((size_t)(b * 16 + s) * 35 + hh) * 64 + c];
    }
    __syncthreads();
    float Wc[35];
    #pragma unroll
    for (int k = 0; k < 35; ++k) Wc[k] = W[k * 256 + tid];
    const float myb = ab[tid], myu = u[tid];
    for (int s = 0; s < 16; ++s) {
        float dot = myb;
        #pragma unroll
        for (int k = 0; k < 35; ++k) dot = fmaf(sh[s * 35 + k], Wc[k], dot);
        float val = tanhf(dot) * myu;
        #pragma unroll
        for (int off = 32; off > 0; off >>= 1) val += __shfl_down(val, off, 64);
        if ((tid & 63) == 0) sred[tid >> 6] = val;
        __syncthreads();
        if (tid == 0) slog[s] = sred[0] + sred[1] + sred[2] + sred[3];
        __syncthreads();
    }
    if (tid == 0) {
        float mx = slog[0];
        for (int s = 1; s < 16; ++s) mx = fmaxf(mx, slog[s]);
        float sum = 0.f, e[16];
        for (int s = 0; s < 16; ++s) { e[s] = expf(slog[s] - mx); sum += e[s]; }
        float inv = 1.f / sum;
        for (int s = 0; s < 16; ++s) salpha[s] = e[s] * inv;
    }
    __syncthreads();
    if (tid < 35) {
        float acc = 0.f;
        for (int s = 0; s < 16; ++s) acc = fmaf(sh[s * 35 + tid], salpha[s], acc);
        out[((size_t)(b * 64 + c)) * 35 + tid] = elu_f(acc);
    }
}

// ---------------------------------------------------------------------------
// Fused GIN stack, split-bf16 (hi/lo) precision: each logical MFMA done as
// 3 products (ah*bh + ah*bl + al*bh) => ~17-bit mantissa, fp32-class error.
// A buffers in LDS: [pingpong][hi/lo][64 rows x 264]. Weights: hi plane at 0,
// lo plane at +wlo. Colsum aggregation fused via quad shuffles in epilogue.
// ---------------------------------------------------------------------------
#define APLANE (64 * 264)

__device__ __forceinline__ void gin_gemm_dev(
    const __bf16* As,                 // hi plane; lo at As+APLANE
    const __bf16* __restrict__ Wg, int Kpad, int wlo, int Kout,
    const float* __restrict__ bias,
    int mode,                 // 0: relu->A   1: relu, +colsum ->A   2: raw->global
    __bf16* Ad, float* __restrict__ outg)
{
    const int lane = threadIdx.x & 63;
    const int wave_o0 = (threadIdx.x >> 6) * 64;
    if (wave_o0 >= ((Kout + 63) & ~63)) return;
    const int m = lane & 15, quad = lane >> 4;

    f32x4 acc[4][4];
    #pragma unroll
    for (int mi = 0; mi < 4; ++mi)
        #pragma unroll
        for (int nj = 0; nj < 4; ++nj)
            acc[mi][nj] = (f32x4){0.f, 0.f, 0.f, 0.f};

    for (int k0 = 0; k0 < Kpad; k0 += 32) {
        bf16x8 ah[4], al[4], bh[4], bl[4];
        #pragma unroll
        for (int mi = 0; mi < 4; ++mi) {
            const __bf16* ap = As + (size_t)(mi * 16 + m) * 264 + k0 + quad * 8;
            ah[mi] = *(const bf16x8*)ap;
            al[mi] = *(const bf16x8*)(ap + APLANE);
        }
        #pragma unroll
        for (int nj = 0; nj < 4; ++nj) {
            const __bf16* wp = Wg + (size_t)(wave_o0 + nj * 16 + m) * Kpad + k0 + quad * 8;
            bh[nj] = *(const bf16x8*)wp;
            bl[nj] = *(const bf16x8*)(wp + wlo);
        }
        #pragma unroll
        for (int mi = 0; mi < 4; ++mi)
            #pragma unroll
            for (int nj = 0; nj < 4; ++nj) {
                acc[mi][nj] = __builtin_amdgcn_mfma_f32_16x16x32_bf16(
                    al[mi], bh[nj], acc[mi][nj], 0, 0, 0);
                acc[mi][nj] = __builtin_amdgcn_mfma_f32_16x16x32_bf16(
                    ah[mi], bl[nj], acc[mi][nj], 0, 0, 0);
                acc[mi][nj] = __builtin_amdgcn_mfma_f32_16x16x32_bf16(
                    ah[mi], bh[nj], acc[mi][nj], 0, 0, 0);
            }
    }

    #pragma unroll
    for (int nj = 0; nj < 4; ++nj) {
        const int o = wave_o0 + nj * 16 + m;
        const bool ovalid = (o < Kout);
        const float bi = ovalid ? bias[o] : 0.f;
        float v[4][4];
        #pragma unroll
        for (int mi = 0; mi < 4; ++mi)
            #pragma unroll
            for (int r = 0; r < 4; ++r)
                v[mi][r] = acc[mi][nj][r] + bi;
        if (mode == 2) {
            if (ovalid) {
                #pragma unroll
                for (int mi = 0; mi < 4; ++mi)
                    #pragma unroll
                    for (int r = 0; r < 4; ++r)
                        outg[(size_t)(mi * 16 + quad * 4 + r) * Kout + o] = v[mi][r];
            }
        } else {
            float s = 0.f;
            #pragma unroll
            for (int mi = 0; mi < 4; ++mi)
                #pragma unroll
                for (int r = 0; r < 4; ++r) {
                    float rv = ovalid ? fmaxf(v[mi][r], 0.f) : 0.f;
                    v[mi][r] = rv;
                    s += rv;
                }
            if (mode == 1) {
                s += __shfl_xor(s, 16, 64);
                s += __shfl_xor(s, 32, 64);
            } else {
                s = 0.f;
            }
            #pragma unroll
            for (int mi = 0; mi < 4; ++mi)
                #pragma unroll
                for (int r = 0; r < 4; ++r) {
                    float a = v[mi][r] + s;
                    __bf16 hi = (__bf16)a;
                    size_t pos = (size_t)(mi * 16 + quad * 4 + r) * 264 + o;
                    Ad[pos] = hi;
                    Ad[APLANE + pos] = (__bf16)(a - (float)hi);
                }
        }
    }
}

__global__ __launch_bounds__(256) void gin_fused(
    const float* __restrict__ ha,
    const __bf16* __restrict__ gW0a, const __bf16* __restrict__ gW0b,
    const __bf16* __restrict__ gW1a, const __bf16* __restrict__ gW1b,
    const __bf16* __restrict__ gW2a, const __bf16* __restrict__ gW2b,
    const float* __restrict__ b0a, const float* __restrict__ b0b,
    const float* __restrict__ b1a, const float* __restrict__ b1b,
    const float* __restrict__ b2a, const float* __restrict__ b2b,
    float* __restrict__ H3)
{
    const int b = blockIdx.x, tid = threadIdx.x;
    __shared__ __align__(16) __bf16 sA[2][2 * APLANE];
    __shared__ float sS[64];
    const float* hab = ha + (size_t)b * 2240;

    if (tid < 64) {
        float s = 0.f;
        if (tid < 35)
            for (int n = 0; n < 64; ++n) s += hab[n * 35 + tid];
        sS[tid] = s;
    }
    __syncthreads();
    for (int idx = tid; idx < 64 * 64; idx += 256) {
        int n = idx >> 6, k = idx & 63;
        float a = (k < 35) ? hab[n * 35 + k] + sS[k] : 0.f;
        __bf16 hi = (__bf16)a;
        sA[0][n * 264 + k] = hi;
        sA[0][APLANE + n * 264 + k] = (__bf16)(a - (float)hi);
    }
    __syncthreads();

    gin_gemm_dev(sA[0], gW0a, 64,  16384, 256, b0a, 0, sA[1], nullptr); __syncthreads();
    gin_gemm_dev(sA[1], gW0b, 256, 65536, 256, b0b, 1, sA[0], nullptr); __syncthreads();
    gin_gemm_dev(sA[0], gW1a, 256, 65536, 256, b1a, 0, sA[1], nullptr); __syncthreads();
    gin_gemm_dev(sA[1], gW1b, 256, 65536, 256, b1b, 1, sA[0], nullptr); __syncthreads();
    gin_gemm_dev(sA[0], gW2a, 256, 16384, 35,  b2a, 0, sA[1], nullptr); __syncthreads();
    gin_gemm_dev(sA[1], gW2b, 64,  4096,  35,  b2b, 2, nullptr, H3 + (size_t)b * 2240);
}

// ---------------------------------------------------------------------------
// Classifier layer 1, split-bf16 MFMA GEMM: [32,2240] x [2240,256] -> [32,256].
// Grid 2 blocks; w1T hi plane + lo plane at +573440.
// ---------------------------------------------------------------------------
__global__ __launch_bounds__(256) void cls1_k(
    const float* __restrict__ H3, const __bf16* __restrict__ w1T,
    const float* __restrict__ b1, float* __restrict__ s1g)
{
    __shared__ __align__(16) __bf16 sF[2][32 * 456];
    const int tid = threadIdx.x;
    const int lane = tid & 63, wave = tid >> 6;
    const int m = lane & 15, quad = lane >> 4;
    const int ow = blockIdx.x * 128 + wave * 32;
    const int WLO = 573440;

    f32x4 acc[2][2];
    #pragma unroll
    for (int mi = 0; mi < 2; ++mi)
        #pragma unroll
        for (int nj = 0; nj < 2; ++nj)
            acc[mi][nj] = (f32x4){0.f, 0.f, 0.f, 0.f};

    for (int kc = 0; kc < 2240; kc += 448) {
        for (int idx = tid; idx < 32 * 448; idx += 256) {
            int bb = idx / 448, k = idx - bb * 448;
            float v = H3[(size_t)bb * 2240 + kc + k];
            __bf16 hi = (__bf16)v;
            sF[0][bb * 456 + k] = hi;
            sF[1][bb * 456 + k] = (__bf16)(v - (float)hi);
        }
        __syncthreads();
        for (int k0 = 0; k0 < 448; k0 += 32) {
            bf16x8 ah[2], al[2], bh[2], bl[2];
            #pragma unroll
            for (int mi = 0; mi < 2; ++mi) {
                ah[mi] = *(const bf16x8*)(sF[0] + (size_t)(mi * 16 + m) * 456 + k0 + quad * 8);
                al[mi] = *(const bf16x8*)(sF[1] + (size_t)(mi * 16 + m) * 456 + k0 + quad * 8);
            }
            #pragma unroll
            for (int nj = 0; nj < 2; ++nj) {
                const __bf16* wp = w1T + (size_t)(ow + nj * 16 + m) * 2240 + kc + k0 + quad * 8;
                bh[nj] = *(const bf16x8*)wp;
                bl[nj] = *(const bf16x8*)(wp + WLO);
            }
            #pragma unroll
            for (int mi = 0; mi < 2; ++mi)
                #pragma unroll
                for (int nj = 0; nj < 2; ++nj) {
                    acc[mi][nj] = __builtin_amdgcn_mfma_f32_16x16x32_bf16(
                        al[mi], bh[nj], acc[mi][nj], 0, 0, 0);
                    acc[mi][nj] = __builtin_amdgcn_mfma_f32_16x16x32_bf16(
                        ah[mi], bl[nj], acc[mi][nj], 0, 0, 0);
                    acc[mi][nj] = __builtin_amdgcn_mfma_f32_16x16x32_bf16(
                        ah[mi], bh[nj], acc[mi][nj], 0, 0, 0);
                }
        }
        __syncthreads();
    }

    #pragma unroll
    for (int nj = 0; nj < 2; ++nj) {
        int o = ow + nj * 16 + m;
        float bi = b1[o];
        #pragma unroll
        for (int mi = 0; mi < 2; ++mi)
            #pragma unroll
            for (int r = 0; r < 4; ++r) {
                int bb = mi * 16 + quad * 4 + r;
                s1g[(size_t)bb * 256 + o] = elu_f(acc[mi][nj][r] + bi);
            }
    }
}

// ---------------------------------------------------------------------------
// Classifier layers 2-4 (tiny, fp32 exact). One block per batch element.
// ---------------------------------------------------------------------------
__global__ __launch_bounds__(256) void cls234_k(
    const float* __restrict__ s1g,
    const float* __restrict__ w2, const float* __restrict__ b2,
    const float* __restrict__ w3, const float* __restrict__ b3,
    const float* __restrict__ w4, const float* __restrict__ b4,
    float* __restrict__ out)
{
    const int b = blockIdx.x, tid = threadIdx.x;
    __shared__ float s1[256];
    __shared__ float part[4][64];
    __shared__ float s2[64];
    __shared__ float s3[16];
    s1[tid] = s1g[(size_t)b * 256 + tid];
    __syncthreads();
    {
        int kg = tid >> 6, o = tid & 63;
        float acc = 0.f;
        for (int k = kg * 64; k < kg * 64 + 64; ++k)
            acc = fmaf(s1[k], w2[k * 64 + o], acc);
        part[kg][o] = acc;
    }
    __syncthreads();
    if (tid < 64) {
        float acc = part[0][tid] + part[1][tid] + part[2][tid] + part[3][tid] + b2[tid];
        s2[tid] = elu_f(acc);
    }
    __syncthreads();
    if (tid < 16) {
        float acc = b3[tid];
        for (int k = 0; k < 64; ++k) acc = fmaf(s2[k], w3[k * 16 + tid], acc);
        s3[tid] = elu_f(acc);
    }
    __syncthreads();
    if (tid < 2) {
        float acc = b4[tid];
        for (int k = 0; k < 16; ++k) acc = fmaf(s3[k], w4[k * 2 + tid], acc);
        out[b * 2 + tid] = acc;
    }
}

// ---------------------------------------------------------------------------
extern "C" void kernel_launch(void* const* d_in, const int* in_sizes, int n_in,
                              void* d_out, int out_size, void* d_ws, size_t ws_size,
                              hipStream_t stream)
{
    const float* x     = (const float*)d_in[0];
    const float* w1    = (const float*)d_in[1];
    const float* b1    = (const float*)d_in[2];
    const float* bn1_g = (const float*)d_in[3];
    const float* bn1_b = (const float*)d_in[4];
    const float* bn1_m = (const float*)d_in[5];
    const float* bn1_v = (const float*)d_in[6];
    const float* w2    = (const float*)d_in[7];
    const float* b2    = (const float*)d_in[8];
    const float* bn2_g = (const float*)d_in[9];
    const float* bn2_b = (const float*)d_in[10];
    const float* bn2_m = (const float*)d_in[11];
    const float* bn2_v = (const float*)d_in[12];
    const float* w3    = (const float*)d_in[13];
    const float* b3    = (const float*)d_in[14];
    const float* w4    = (const float*)d_in[15];
    const float* b4    = (const float*)d_in[16];
    const float* attn_w = (const float*)d_in[17];
    const float* attn_b = (const float*)d_in[18];
    const float* attn_u = (const float*)d_in[19];
    const float* g0_w1 = (const float*)d_in[20];
    const float* g0_b1 = (const float*)d_in[21];
    const float* g0_w2 = (const float*)d_in[22];
    const float* g0_b2 = (const float*)d_in[23];
    const float* g1_w1 = (const float*)d_in[24];
    const float* g1_b1 = (const float*)d_in[25];
    const float* g1_w2 = (const float*)d_in[26];
    const float* g1_b2 = (const float*)d_in[27];
    const float* g2_w1 = (const float*)d_in[28];
    const float* g2_b1 = (const float*)d_in[29];
    const float* g2_w2 = (const float*)d_in[30];
    const float* g2_b2 = (const float*)d_in[31];
    const float* c_w1  = (const float*)d_in[32];
    const float* c_b1  = (const float*)d_in[33];
    const float* c_w2  = (const float*)d_in[34];
    const float* c_b2  = (const float*)d_in[35];
    const float* c_w3  = (const float*)d_in[36];
    const float* c_b3  = (const float*)d_in[37];
    const float* c_w4  = (const float*)d_in[38];
    const float* c_b4  = (const float*)d_in[39];
    float* out = (float*)d_out;

    char* ws = (char*)d_ws;
    __bf16* wT1  = (__bf16*)(ws + 0);
    __bf16* wT2  = (__bf16*)(ws + 163840);
    __bf16* wT3  = (__bf16*)(ws + 327680);
    __bf16* wT4  = (__bf16*)(ws + 376832);
    __bf16* h1   = (__bf16*)(ws + 425984);     // [512][192][64]
    __bf16* h2   = (__bf16*)(ws + 13008896);   // [512][87][64]
    __bf16* h3   = (__bf16*)(ws + 18710528);   // [512][82][64]
    __bf16* h4   = (__bf16*)(ws + 24084480);   // [512][35][64]
    float*  ha   = (float*)(ws + 26378240);    // [32][64][35]
    __bf16* gW0a = (__bf16*)(ws + 26664960);   // hi+lo [256][64]   65536 B
    __bf16* gW0b = (__bf16*)(ws + 26730496);   // hi+lo [256][256] 262144 B
    __bf16* gW1a = (__bf16*)(ws + 26992640);
    __bf16* gW1b = (__bf16*)(ws + 27254784);
    __bf16* gW2a = (__bf16*)(ws + 27516928);   // hi+lo [64][256]   65536 B
    __bf16* gW2b = (__bf16*)(ws + 27582464);   // hi+lo [64][64]    16384 B
    __bf16* w1T  = (__bf16*)(ws + 27598848);   // hi+lo [256][2240] 2293760 B
    float*  H3   = (float*)(ws + 29892608);    // [32][2240]
    float*  s1g  = (float*)(ws + 30179328);    // [32][256]

    prep_weights<<<dim3(832), dim3(256), 0, stream>>>(w1, w2, w3, w4, wT1, wT2, wT3, wT4);
    prep_tr<<<dim3(197), dim3(256), 0, stream>>>(g0_w1, g0_w2, g1_w1, g1_w2, g2_w1, g2_w2,
                                                 c_w1, gW0a, gW0b, gW1a, gW1b, gW2a, gW2b, w1T);

    conv_mfma<20, 2, 1, true, 0, 1, 4, 400, 192><<<dim3(512), dim3(256), 0, stream>>>(
        x, wT1, b1, bn1_g, bn1_b, bn1_m, bn1_v, h1);
    conv_mfma<20, 2, 0, true, 1, 1, 2, 192, 87><<<dim3(512), dim3(128), 0, stream>>>(
        h1, wT2, b2, bn2_g, bn2_b, bn2_m, bn2_v, h2);
    conv_mfma<6, 1, 0, false, 1, 1, 2, 87, 82><<<dim3(512), dim3(128), 0, stream>>>(
        h2, wT3, b3, nullptr, nullptr, nullptr, nullptr, h3);
    conv_mfma<6, 1, 0, false, 2, 2, 1, 40, 35><<<dim3(256), dim3(128), 0, stream>>>(
        h3, wT4, b4, nullptr, nullptr, nullptr, nullptr, h4);

    attn_pool_k<<<dim3(2048), dim3(256), 0, stream>>>(h4, attn_w, attn_b, attn_u, ha);

    gin_fused<<<dim3(32), dim3(256), 0, stream>>>(
        ha, gW0a, gW0b, gW1a, gW1b, gW2a, gW2b,
        g0_b1, g0_b2, g1_b1, g1_b2, g2_b1, g2_b2, H3);

    cls1_k<<<dim3(2), dim3(256), 0, stream>>>(H3, w1T, c_b1, s1g);
    cls234_k<<<dim3(32), dim3(256), 0, stream>>>(s1g, c_w2, c_b2, c_w3, c_b3, c_w4, c_b4, out);
}

// Round 5
// 488.206 us; speedup vs baseline: 2.0588x; 1.0748x over previous
//
#include <hip/hip_runtime.h>
#include <math.h>

typedef __attribute__((ext_vector_type(8))) __bf16 bf16x8;
typedef __attribute__((ext_vector_type(4))) float f32x4;

__device__ __forceinline__ float elu_f(float v) {
    return v > 0.f ? v : (expf(v) - 1.f);
}

// ---------------------------------------------------------------------------
// Conv weight reorder: w[co][ci][K] fp32 -> wT[k][co][ci] bf16 (all 4 convs).
// ---------------------------------------------------------------------------
__global__ __launch_bounds__(256) void prep_weights(
    const float* __restrict__ w1, const float* __restrict__ w2,
    const float* __restrict__ w3, const float* __restrict__ w4,
    __bf16* __restrict__ t1, __bf16* __restrict__ t2,
    __bf16* __restrict__ t3, __bf16* __restrict__ t4)
{
    int idx = blockIdx.x * 256 + threadIdx.x;
    if (idx < 81920) {
        int k = idx / 4096, r = idx - k * 4096, co = r >> 6, ci = r & 63;
        t1[idx] = (__bf16)w1[(co * 64 + ci) * 20 + k];
    } else if (idx < 163840) {
        int j = idx - 81920;
        int k = j / 4096, r = j - k * 4096, co = r >> 6, ci = r & 63;
        t2[j] = (__bf16)w2[(co * 64 + ci) * 20 + k];
    } else if (idx < 188416) {
        int j = idx - 163840;
        int k = j / 4096, r = j - k * 4096, co = r >> 6, ci = r & 63;
        t3[j] = (__bf16)w3[(co * 64 + ci) * 6 + k];
    } else if (idx < 212992) {
        int j = idx - 188416;
        int k = j / 4096, r = j - k * 4096, co = r >> 6, ci = r & 63;
        t4[j] = (__bf16)w4[(co * 64 + ci) * 6 + k];
    }
}

// ---------------------------------------------------------------------------
// Tiled transpose+convert with hi/lo split: src fp32 [K][O] ->
// dst bf16 [Opad][Kpad] hi plane at 0, lo plane at Opad*Kpad (zero pad).
// GIN weights only (classifier is fp32 now). 57 blocks.
// ---------------------------------------------------------------------------
__global__ __launch_bounds__(256) void prep_tr(
    const float* __restrict__ g0w1, const float* __restrict__ g0w2,
    const float* __restrict__ g1w1, const float* __restrict__ g1w2,
    const float* __restrict__ g2w1, const float* __restrict__ g2w2,
    __bf16* __restrict__ d0, __bf16* __restrict__ d1, __bf16* __restrict__ d2,
    __bf16* __restrict__ d3, __bf16* __restrict__ d4, __bf16* __restrict__ d5)
{
    int bid = blockIdx.x;
    const float* src; __bf16* dst; int K, O, Kpad, Opad, tile;
    if (bid < 4)       { src = g0w1; dst = d0; K = 35;   O = 256; Kpad = 64;   Opad = 256; tile = bid; }
    else if (bid < 20) { src = g0w2; dst = d1; K = 256;  O = 256; Kpad = 256;  Opad = 256; tile = bid - 4; }
    else if (bid < 36) { src = g1w1; dst = d2; K = 256;  O = 256; Kpad = 256;  Opad = 256; tile = bid - 20; }
    else if (bid < 52) { src = g1w2; dst = d3; K = 256;  O = 256; Kpad = 256;  Opad = 256; tile = bid - 36; }
    else if (bid < 56) { src = g2w1; dst = d4; K = 256;  O = 35;  Kpad = 256;  Opad = 64;  tile = bid - 52; }
    else               { src = g2w2; dst = d5; K = 35;   O = 35;  Kpad = 64;   Opad = 64;  tile = 0; }
    int ktiles = Kpad >> 6;
    int ot = tile / ktiles, kt = tile - ot * ktiles;
    int k0 = kt * 64, o0 = ot * 64;
    size_t LOFF = (size_t)Opad * Kpad;
    __shared__ float tl[64][68];
    int c = threadIdx.x & 63, rr = threadIdx.x >> 6;
    #pragma unroll
    for (int it = 0; it < 16; ++it) {
        int r = rr + it * 4;
        int kk = k0 + r, oo = o0 + c;
        tl[r][c] = (kk < K && oo < O) ? src[(size_t)kk * O + oo] : 0.f;
    }
    __syncthreads();
    #pragma unroll
    for (int it = 0; it < 16; ++it) {
        int r = rr + it * 4;
        float v = tl[c][r];
        __bf16 hi = (__bf16)v;
        float lo = v - (float)hi;
        size_t pos = (size_t)(o0 + r) * Kpad + k0 + c;
        dst[pos] = hi;
        dst[LOFF + pos] = (__bf16)lo;
    }
}

// ---------------------------------------------------------------------------
// MFMA conv1d, Cin=Cout=64. Output [n][t][64co] bf16.
// Input staged to LDS ONCE; weights B-fragments direct from global wT
// (L2-hot) -> zero barriers in the K loop.
// ---------------------------------------------------------------------------
template<int K, int STRIDE, int PAD, bool DO_BN, int IMODE,
         int NPB, int TPN, int LIN, int LOUT>
__global__ __launch_bounds__(NPB * TPN * 64, 2) void conv_mfma(
    const void* __restrict__ xin, const __bf16* __restrict__ wT,
    const float* __restrict__ bias,
    const float* __restrict__ bn_g, const float* __restrict__ bn_b,
    const float* __restrict__ bn_m, const float* __restrict__ bn_v,
    __bf16* __restrict__ y)
{
    constexpr int THREADS = NPB * TPN * 64;
    constexpr int TBLK  = TPN * 48;
    constexpr int VSPAN = STRIDE * (TBLK - 1) + K;
    constexpr int NBUF  = (STRIDE == 2) ? 2 : 1;
    constexpr int ROWS  = (VSPAN + NBUF - 1) / NBUF;
    __shared__ __align__(16) __bf16 sx[NPB * NBUF * ROWS * 72];

    const int tid = threadIdx.x;
    const int nb  = blockIdx.x * NPB;

    if constexpr (IMODE == 0) {
        const float* xg = (const float*)xin + (size_t)nb * 64 * LIN;
        for (int idx = tid; idx < 64 * VSPAN; idx += THREADS) {
            int ci = idx / VSPAN, v = idx - ci * VSPAN;
            int pos = v - PAD;
            float val = (pos >= 0 && pos < LIN) ? xg[ci * LIN + pos] : 0.f;
            sx[((v & (NBUF - 1)) * ROWS + (v >> (NBUF - 1))) * 72 + ci] = (__bf16)val;
        }
    } else {
        const __bf16* xg = (const __bf16*)xin;
        for (int idx = tid; idx < NPB * VSPAN * 8; idx += THREADS) {
            int n_l = idx / (VSPAN * 8);
            int r   = idx - n_l * (VSPAN * 8);
            int v = r >> 3, c8 = (r & 7) * 8;
            int buf = (STRIDE == 2) ? (v & 1) : 0;
            int row = (STRIDE == 2) ? (v >> 1) : v;
            __bf16* dst = sx + ((size_t)(n_l * NBUF + buf) * ROWS + row) * 72 + c8;
            if constexpr (IMODE == 1) {
                if (v < LIN) {
                    const __bf16* src = xg + (((size_t)(nb + n_l) * LIN + v) * 64 + c8);
                    *(uint4*)dst = *(const uint4*)src;
                } else {
                    #pragma unroll
                    for (int e = 0; e < 8; ++e) dst[e] = (__bf16)0.f;
                }
            } else {
                if (v < LIN) {
                    const __bf16* s0 = xg + (((size_t)(nb + n_l) * 82 + 2 * v) * 64 + c8);
                    #pragma unroll
                    for (int e = 0; e < 8; ++e)
                        dst[e] = (__bf16)(((float)s0[e] + (float)s0[64 + e] +
                                           (float)s0[128 + e]) * (1.f / 3.f));
                } else {
                    #pragma unroll
                    for (int e = 0; e < 8; ++e) dst[e] = (__bf16)0.f;
                }
            }
        }
    }
    __syncthreads();

    const int wave = tid >> 6, lane = tid & 63;
    const int n_l  = wave / TPN, tile = wave - n_l * TPN;
    const int m    = lane & 15, quad = lane >> 4;
    const __bf16* sxn = sx + (size_t)n_l * NBUF * ROWS * 72;

    f32x4 acc[3][4];
    #pragma unroll
    for (int mi = 0; mi < 3; ++mi)
        #pragma unroll
        for (int nj = 0; nj < 4; ++nj)
            acc[mi][nj] = (f32x4){0.f, 0.f, 0.f, 0.f};

    #pragma unroll 2
    for (int kp = 0; kp < K; ++kp) {
        const int buf    = (STRIDE == 2) ? (kp & 1) : 0;
        const int rowoff = (STRIDE == 2) ? (kp >> 1) : kp;
        const __bf16* abase = sxn + ((size_t)buf * ROWS + tile * 48 + m + rowoff) * 72;
        const __bf16* wbase = wT + (size_t)kp * 4096 + m * 64;
        #pragma unroll
        for (int s = 0; s < 2; ++s) {
            bf16x8 af[3], bfr[4];
            #pragma unroll
            for (int mi = 0; mi < 3; ++mi)
                af[mi] = *(const bf16x8*)(abase + mi * (16 * 72) + s * 32 + quad * 8);
            #pragma unroll
            for (int nj = 0; nj < 4; ++nj)
                bfr[nj] = *(const bf16x8*)(wbase + nj * 1024 + s * 32 + quad * 8);
            #pragma unroll
            for (int mi = 0; mi < 3; ++mi)
                #pragma unroll
                for (int nj = 0; nj < 4; ++nj)
                    acc[mi][nj] = __builtin_amdgcn_mfma_f32_16x16x32_bf16(
                        af[mi], bfr[nj], acc[mi][nj], 0, 0, 0);
        }
    }

    #pragma unroll
    for (int nj = 0; nj < 4; ++nj) {
        const int co = nj * 16 + m;
        const float bi = bias[co];
        float scale = 1.f, shift = 0.f;
        if constexpr (DO_BN) {
            float inv = bn_g[co] / sqrtf(bn_v[co] + 1e-5f);
            scale = inv; shift = bn_b[co] - bn_m[co] * inv;
        }
        #pragma unroll
        for (int mi = 0; mi < 3; ++mi) {
            #pragma unroll
            for (int r = 0; r < 4; ++r) {
                int t = tile * 48 + mi * 16 + quad * 4 + r;
                if (t < LOUT) {
                    float v = acc[mi][nj][r] + bi;
                    v = elu_f(v);
                    if constexpr (DO_BN) v = v * scale + shift;
                    y[((size_t)(nb + n_l) * LOUT + t) * 64 + co] = (__bf16)v;
                }
            }
        }
    }
}

// ---------------------------------------------------------------------------
// Attention pooling over crop dim. One block per (b,c). h: [512][35][64] bf16.
// ---------------------------------------------------------------------------
__global__ __launch_bounds__(256) void attn_pool_k(
    const __bf16* __restrict__ h, const float* __restrict__ W,
    const float* __restrict__ ab, const float* __restrict__ u,
    float* __restrict__ out)
{
    const int b = blockIdx.x >> 6;
    const int c = blockIdx.x & 63;
    __shared__ float sh[16 * 35];
    __shared__ float slog[16];
    __shared__ float sred[4];
    __shared__ float salpha[16];
    const int tid = threadIdx.x;
    for (int idx = tid; idx < 16 * 35; idx += 256) {
        int s = idx / 35, hh = idx - s * 35;
        sh[idx] = (float)h[((size_t)(b * 16 + s) * 35 + hh) * 64 + c];
    }
    __syncthreads();
    float Wc[35];
    #pragma unroll
    for (int k = 0; k < 35; ++k) Wc[k] = W[k * 256 + tid];
    const float myb = ab[tid], myu = u[tid];
    for (int s = 0; s < 16; ++s) {
        float dot = myb;
        #pragma unroll
        for (int k = 0; k < 35; ++k) dot = fmaf(sh[s * 35 + k], Wc[k], dot);
        float val = tanhf(dot) * myu;
        #pragma unroll
        for (int off = 32; off > 0; off >>= 1) val += __shfl_down(val, off, 64);
        if ((tid & 63) == 0) sred[tid >> 6] = val;
        __syncthreads();
        if (tid == 0) slog[s] = sred[0] + sred[1] + sred[2] + sred[3];
        __syncthreads();
    }
    if (tid == 0) {
        float mx = slog[0];
        for (int s = 1; s < 16; ++s) mx = fmaxf(mx, slog[s]);
        float sum = 0.f, e[16];
        for (int s = 0; s < 16; ++s) { e[s] = expf(slog[s] - mx); sum += e[s]; }
        float inv = 1.f / sum;
        for (int s = 0; s < 16; ++s) salpha[s] = e[s] * inv;
    }
    __syncthreads();
    if (tid < 35) {
        float acc = 0.f;
        for (int s = 0; s < 16; ++s) acc = fmaf(sh[s * 35 + tid], salpha[s], acc);
        out[((size_t)(b * 64 + c)) * 35 + tid] = elu_f(acc);
    }
}

// ---------------------------------------------------------------------------
// Fused GIN stack, split-bf16 (hi/lo) precision (3 MFMA per logical product).
// ---------------------------------------------------------------------------
#define APLANE (64 * 264)

__device__ __forceinline__ void gin_gemm_dev(
    const __bf16* As,                 // hi plane; lo at As+APLANE
    const __bf16* __restrict__ Wg, int Kpad, int wlo, int Kout,
    const float* __restrict__ bias,
    int mode,                 // 0: relu->A   1: relu, +colsum ->A   2: raw->global
    __bf16* Ad, float* __restrict__ outg)
{
    const int lane = threadIdx.x & 63;
    const int wave_o0 = (threadIdx.x >> 6) * 64;
    if (wave_o0 >= ((Kout + 63) & ~63)) return;
    const int m = lane & 15, quad = lane >> 4;

    f32x4 acc[4][4];
    #pragma unroll
    for (int mi = 0; mi < 4; ++mi)
        #pragma unroll
        for (int nj = 0; nj < 4; ++nj)
            acc[mi][nj] = (f32x4){0.f, 0.f, 0.f, 0.f};

    for (int k0 = 0; k0 < Kpad; k0 += 32) {
        bf16x8 ah[4], al[4], bh[4], bl[4];
        #pragma unroll
        for (int mi = 0; mi < 4; ++mi) {
            const __bf16* ap = As + (size_t)(mi * 16 + m) * 264 + k0 + quad * 8;
            ah[mi] = *(const bf16x8*)ap;
            al[mi] = *(const bf16x8*)(ap + APLANE);
        }
        #pragma unroll
        for (int nj = 0; nj < 4; ++nj) {
            const __bf16* wp = Wg + (size_t)(wave_o0 + nj * 16 + m) * Kpad + k0 + quad * 8;
            bh[nj] = *(const bf16x8*)wp;
            bl[nj] = *(const bf16x8*)(wp + wlo);
        }
        #pragma unroll
        for (int mi = 0; mi < 4; ++mi)
            #pragma unroll
            for (int nj = 0; nj < 4; ++nj) {
                acc[mi][nj] = __builtin_amdgcn_mfma_f32_16x16x32_bf16(
                    al[mi], bh[nj], acc[mi][nj], 0, 0, 0);
                acc[mi][nj] = __builtin_amdgcn_mfma_f32_16x16x32_bf16(
                    ah[mi], bl[nj], acc[mi][nj], 0, 0, 0);
                acc[mi][nj] = __builtin_amdgcn_mfma_f32_16x16x32_bf16(
                    ah[mi], bh[nj], acc[mi][nj], 0, 0, 0);
            }
    }

    #pragma unroll
    for (int nj = 0; nj < 4; ++nj) {
        const int o = wave_o0 + nj * 16 + m;
        const bool ovalid = (o < Kout);
        const float bi = ovalid ? bias[o] : 0.f;
        float v[4][4];
        #pragma unroll
        for (int mi = 0; mi < 4; ++mi)
            #pragma unroll
            for (int r = 0; r < 4; ++r)
                v[mi][r] = acc[mi][nj][r] + bi;
        if (mode == 2) {
            if (ovalid) {
                #pragma unroll
                for (int mi = 0; mi < 4; ++mi)
                    #pragma unroll
                    for (int r = 0; r < 4; ++r)
                        outg[(size_t)(mi * 16 + quad * 4 + r) * Kout + o] = v[mi][r];
            }
        } else {
            float s = 0.f;
            #pragma unroll
            for (int mi = 0; mi < 4; ++mi)
                #pragma unroll
                for (int r = 0; r < 4; ++r) {
                    float rv = ovalid ? fmaxf(v[mi][r], 0.f) : 0.f;
                    v[mi][r] = rv;
                    s += rv;
                }
            if (mode == 1) {
                s += __shfl_xor(s, 16, 64);
                s += __shfl_xor(s, 32, 64);
            } else {
                s = 0.f;
            }
            #pragma unroll
            for (int mi = 0; mi < 4; ++mi)
                #pragma unroll
                for (int r = 0; r < 4; ++r) {
                    float a = v[mi][r] + s;
                    __bf16 hi = (__bf16)a;
                    size_t pos = (size_t)(mi * 16 + quad * 4 + r) * 264 + o;
                    Ad[pos] = hi;
                    Ad[APLANE + pos] = (__bf16)(a - (float)hi);
                }
        }
    }
}

__global__ __launch_bounds__(256) void gin_fused(
    const float* __restrict__ ha,
    const __bf16* __restrict__ gW0a, const __bf16* __restrict__ gW0b,
    const __bf16* __restrict__ gW1a, const __bf16* __restrict__ gW1b,
    const __bf16* __restrict__ gW2a, const __bf16* __restrict__ gW2b,
    const float* __restrict__ b0a, const float* __restrict__ b0b,
    const float* __restrict__ b1a, const float* __restrict__ b1b,
    const float* __restrict__ b2a, const float* __restrict__ b2b,
    float* __restrict__ H3)
{
    const int b = blockIdx.x, tid = threadIdx.x;
    __shared__ __align__(16) __bf16 sA[2][2 * APLANE];
    __shared__ float sS[64];
    const float* hab = ha + (size_t)b * 2240;

    if (tid < 64) {
        float s = 0.f;
        if (tid < 35)
            for (int n = 0; n < 64; ++n) s += hab[n * 35 + tid];
        sS[tid] = s;
    }
    __syncthreads();
    for (int idx = tid; idx < 64 * 64; idx += 256) {
        int n = idx >> 6, k = idx & 63;
        float a = (k < 35) ? hab[n * 35 + k] + sS[k] : 0.f;
        __bf16 hi = (__bf16)a;
        sA[0][n * 264 + k] = hi;
        sA[0][APLANE + n * 264 + k] = (__bf16)(a - (float)hi);
    }
    __syncthreads();

    gin_gemm_dev(sA[0], gW0a, 64,  16384, 256, b0a, 0, sA[1], nullptr); __syncthreads();
    gin_gemm_dev(sA[1], gW0b, 256, 65536, 256, b0b, 1, sA[0], nullptr); __syncthreads();
    gin_gemm_dev(sA[0], gW1a, 256, 65536, 256, b1a, 0, sA[1], nullptr); __syncthreads();
    gin_gemm_dev(sA[1], gW1b, 256, 65536, 256, b1b, 1, sA[0], nullptr); __syncthreads();
    gin_gemm_dev(sA[0], gW2a, 256, 16384, 35,  b2a, 0, sA[1], nullptr); __syncthreads();
    gin_gemm_dev(sA[1], gW2b, 64,  4096,  35,  b2b, 2, nullptr, H3 + (size_t)b * 2240);
}

// ---------------------------------------------------------------------------
// Classifier layer 1, fp32 exact, split across outputs for parallelism:
// grid 32 blocks x 8 outputs; thread = (batch b, output lane). H3 k-chunks
// staged in LDS (broadcast); w1 column reads are L2-hot.
// ---------------------------------------------------------------------------
__global__ __launch_bounds__(256) void cls1_split_k(
    const float* __restrict__ H3, const float* __restrict__ w1,
    const float* __restrict__ b1, float* __restrict__ s1g)
{
    __shared__ float sH[32 * 560];
    const int tid = threadIdx.x;
    const int o = blockIdx.x * 8 + (tid & 7);
    const int b = tid >> 3;
    float a0 = 0.f, a1 = 0.f, a2 = 0.f, a3 = 0.f;
    for (int kc = 0; kc < 2240; kc += 560) {
        for (int i = tid; i < 32 * 560; i += 256) {
            int bb = i / 560, kk = i - bb * 560;
            sH[bb * 560 + kk] = H3[(size_t)bb * 2240 + kc + kk];
        }
        __syncthreads();
        const float* hr = sH + b * 560;
        const float* wr = w1 + (size_t)kc * 256 + o;
        #pragma unroll 4
        for (int k = 0; k < 560; k += 4) {
            a0 = fmaf(hr[k],     wr[(size_t)k * 256],       a0);
            a1 = fmaf(hr[k + 1], wr[(size_t)(k + 1) * 256], a1);
            a2 = fmaf(hr[k + 2], wr[(size_t)(k + 2) * 256], a2);
            a3 = fmaf(hr[k + 3], wr[(size_t)(k + 3) * 256], a3);
        }
        __syncthreads();
    }
    s1g[(size_t)b * 256 + o] = elu_f(a0 + a1 + a2 + a3 + b1[o]);
}

// ---------------------------------------------------------------------------
// Classifier layers 2-4 (tiny, fp32 exact). One block per batch element.
// ---------------------------------------------------------------------------
__global__ __launch_bounds__(256) void cls234_k(
    const float* __restrict__ s1g,
    const float* __restrict__ w2, const float* __restrict__ b2,
    const float* __restrict__ w3, const float* __restrict__ b3,
    const float* __restrict__ w4, const float* __restrict__ b4,
    float* __restrict__ out)
{
    const int b = blockIdx.x, tid = threadIdx.x;
    __shared__ float s1[256];
    __shared__ float part[4][64];
    __shared__ float s2[64];
    __shared__ float s3[16];
    s1[tid] = s1g[(size_t)b * 256 + tid];
    __syncthreads();
    {
        int kg = tid >> 6, o = tid & 63;
        float acc = 0.f;
        for (int k = kg * 64; k < kg * 64 + 64; ++k)
            acc = fmaf(s1[k], w2[k * 64 + o], acc);
        part[kg][o] = acc;
    }
    __syncthreads();
    if (tid < 64) {
        float acc = part[0][tid] + part[1][tid] + part[2][tid] + part[3][tid] + b2[tid];
        s2[tid] = elu_f(acc);
    }
    __syncthreads();
    if (tid < 16) {
        float acc = b3[tid];
        for (int k = 0; k < 64; ++k) acc = fmaf(s2[k], w3[k * 16 + tid], acc);
        s3[tid] = elu_f(acc);
    }
    __syncthreads();
    if (tid < 2) {
        float acc = b4[tid];
        for (int k = 0; k < 16; ++k) acc = fmaf(s3[k], w4[k * 2 + tid], acc);
        out[b * 2 + tid] = acc;
    }
}

// ---------------------------------------------------------------------------
extern "C" void kernel_launch(void* const* d_in, const int* in_sizes, int n_in,
                              void* d_out, int out_size, void* d_ws, size_t ws_size,
                              hipStream_t stream)
{
    const float* x     = (const float*)d_in[0];
    const float* w1    = (const float*)d_in[1];
    const float* b1    = (const float*)d_in[2];
    const float* bn1_g = (const float*)d_in[3];
    const float* bn1_b = (const float*)d_in[4];
    const float* bn1_m = (const float*)d_in[5];
    const float* bn1_v = (const float*)d_in[6];
    const float* w2    = (const float*)d_in[7];
    const float* b2    = (const float*)d_in[8];
    const float* bn2_g = (const float*)d_in[9];
    const float* bn2_b = (const float*)d_in[10];
    const float* bn2_m = (const float*)d_in[11];
    const float* bn2_v = (const float*)d_in[12];
    const float* w3    = (const float*)d_in[13];
    const float* b3    = (const float*)d_in[14];
    const float* w4    = (const float*)d_in[15];
    const float* b4    = (const float*)d_in[16];
    const float* attn_w = (const float*)d_in[17];
    const float* attn_b = (const float*)d_in[18];
    const float* attn_u = (const float*)d_in[19];
    const float* g0_w1 = (const float*)d_in[20];
    const float* g0_b1 = (const float*)d_in[21];
    const float* g0_w2 = (const float*)d_in[22];
    const float* g0_b2 = (const float*)d_in[23];
    const float* g1_w1 = (const float*)d_in[24];
    const float* g1_b1 = (const float*)d_in[25];
    const float* g1_w2 = (const float*)d_in[26];
    const float* g1_b2 = (const float*)d_in[27];
    const float* g2_w1 = (const float*)d_in[28];
    const float* g2_b1 = (const float*)d_in[29];
    const float* g2_w2 = (const float*)d_in[30];
    const float* g2_b2 = (const float*)d_in[31];
    const float* c_w1  = (const float*)d_in[32];
    const float* c_b1  = (const float*)d_in[33];
    const float* c_w2  = (const float*)d_in[34];
    const float* c_b2  = (const float*)d_in[35];
    const float* c_w3  = (const float*)d_in[36];
    const float* c_b3  = (const float*)d_in[37];
    const float* c_w4  = (const float*)d_in[38];
    const float* c_b4  = (const float*)d_in[39];
    float* out = (float*)d_out;

    char* ws = (char*)d_ws;
    __bf16* wT1  = (__bf16*)(ws + 0);
    __bf16* wT2  = (__bf16*)(ws + 163840);
    __bf16* wT3  = (__bf16*)(ws + 327680);
    __bf16* wT4  = (__bf16*)(ws + 376832);
    __bf16* h1   = (__bf16*)(ws + 425984);     // [512][192][64]
    __bf16* h2   = (__bf16*)(ws + 13008896);   // [512][87][64]
    __bf16* h3   = (__bf16*)(ws + 18710528);   // [512][82][64]
    __bf16* h4   = (__bf16*)(ws + 24084480);   // [512][35][64]
    float*  ha   = (float*)(ws + 26378240);    // [32][64][35]
    __bf16* gW0a = (__bf16*)(ws + 26664960);   // hi+lo [256][64]   65536 B
    __bf16* gW0b = (__bf16*)(ws + 26730496);   // hi+lo [256][256] 262144 B
    __bf16* gW1a = (__bf16*)(ws + 26992640);
    __bf16* gW1b = (__bf16*)(ws + 27254784);
    __bf16* gW2a = (__bf16*)(ws + 27516928);   // hi+lo [64][256]   65536 B
    __bf16* gW2b = (__bf16*)(ws + 27582464);   // hi+lo [64][64]    16384 B
    float*  H3   = (float*)(ws + 27598848);    // [32][2240]
    float*  s1g  = (float*)(ws + 27885568);    // [32][256]

    prep_weights<<<dim3(832), dim3(256), 0, stream>>>(w1, w2, w3, w4, wT1, wT2, wT3, wT4);
    prep_tr<<<dim3(57), dim3(256), 0, stream>>>(g0_w1, g0_w2, g1_w1, g1_w2, g2_w1, g2_w2,
                                                gW0a, gW0b, gW1a, gW1b, gW2a, gW2b);

    conv_mfma<20, 2, 1, true, 0, 1, 4, 400, 192><<<dim3(512), dim3(256), 0, stream>>>(
        x, wT1, b1, bn1_g, bn1_b, bn1_m, bn1_v, h1);
    conv_mfma<20, 2, 0, true, 1, 1, 2, 192, 87><<<dim3(512), dim3(128), 0, stream>>>(
        h1, wT2, b2, bn2_g, bn2_b, bn2_m, bn2_v, h2);
    conv_mfma<6, 1, 0, false, 1, 1, 2, 87, 82><<<dim3(512), dim3(128), 0, stream>>>(
        h2, wT3, b3, nullptr, nullptr, nullptr, nullptr, h3);
    conv_mfma<6, 1, 0, false, 2, 2, 1, 40, 35><<<dim3(256), dim3(128), 0, stream>>>(
        h3, wT4, b4, nullptr, nullptr, nullptr, nullptr, h4);

    attn_pool_k<<<dim3(2048), dim3(256), 0, stream>>>(h4, attn_w, attn_b, attn_u, ha);

    gin_fused<<<dim3(32), dim3(256), 0, stream>>>(
        ha, gW0a, gW0b, gW1a, gW1b, gW2a, gW2b,
        g0_b1, g0_b2, g1_b1, g1_b2, g2_b1, g2_b2, H3);

    cls1_split_k<<<dim3(32), dim3(256), 0, stream>>>(H3, c_w1, c_b1, s1g);
    cls234_k<<<dim3(32), dim3(256), 0, stream>>>(s1g, c_w2, c_b2, c_w3, c_b3, c_w4, c_b4, out);
}

// Round 6
// 411.961 us; speedup vs baseline: 2.4399x; 1.1851x over previous
//
#include <hip/hip_runtime.h>
#include <math.h>

typedef __attribute__((ext_vector_type(8))) __bf16 bf16x8;
typedef __attribute__((ext_vector_type(4))) float f32x4;

__device__ __forceinline__ float elu_f(float v) {
    return v > 0.f ? v : (expf(v) - 1.f);
}

// ---------------------------------------------------------------------------
// Conv weight reorder: w[co][ci][K] fp32 -> wT[k][co][ci] bf16 (all 4 convs).
// ---------------------------------------------------------------------------
__global__ __launch_bounds__(256) void prep_weights(
    const float* __restrict__ w1, const float* __restrict__ w2,
    const float* __restrict__ w3, const float* __restrict__ w4,
    __bf16* __restrict__ t1, __bf16* __restrict__ t2,
    __bf16* __restrict__ t3, __bf16* __restrict__ t4)
{
    int idx = blockIdx.x * 256 + threadIdx.x;
    if (idx < 81920) {
        int k = idx / 4096, r = idx - k * 4096, co = r >> 6, ci = r & 63;
        t1[idx] = (__bf16)w1[(co * 64 + ci) * 20 + k];
    } else if (idx < 163840) {
        int j = idx - 81920;
        int k = j / 4096, r = j - k * 4096, co = r >> 6, ci = r & 63;
        t2[j] = (__bf16)w2[(co * 64 + ci) * 20 + k];
    } else if (idx < 188416) {
        int j = idx - 163840;
        int k = j / 4096, r = j - k * 4096, co = r >> 6, ci = r & 63;
        t3[j] = (__bf16)w3[(co * 64 + ci) * 6 + k];
    } else if (idx < 212992) {
        int j = idx - 188416;
        int k = j / 4096, r = j - k * 4096, co = r >> 6, ci = r & 63;
        t4[j] = (__bf16)w4[(co * 64 + ci) * 6 + k];
    }
}

// ---------------------------------------------------------------------------
// Tiled transpose+convert with hi/lo split for GIN weights. 57 blocks.
// ---------------------------------------------------------------------------
__global__ __launch_bounds__(256) void prep_tr(
    const float* __restrict__ g0w1, const float* __restrict__ g0w2,
    const float* __restrict__ g1w1, const float* __restrict__ g1w2,
    const float* __restrict__ g2w1, const float* __restrict__ g2w2,
    __bf16* __restrict__ d0, __bf16* __restrict__ d1, __bf16* __restrict__ d2,
    __bf16* __restrict__ d3, __bf16* __restrict__ d4, __bf16* __restrict__ d5)
{
    int bid = blockIdx.x;
    const float* src; __bf16* dst; int K, O, Kpad, Opad, tile;
    if (bid < 4)       { src = g0w1; dst = d0; K = 35;   O = 256; Kpad = 64;   Opad = 256; tile = bid; }
    else if (bid < 20) { src = g0w2; dst = d1; K = 256;  O = 256; Kpad = 256;  Opad = 256; tile = bid - 4; }
    else if (bid < 36) { src = g1w1; dst = d2; K = 256;  O = 256; Kpad = 256;  Opad = 256; tile = bid - 20; }
    else if (bid < 52) { src = g1w2; dst = d3; K = 256;  O = 256; Kpad = 256;  Opad = 256; tile = bid - 36; }
    else if (bid < 56) { src = g2w1; dst = d4; K = 256;  O = 35;  Kpad = 256;  Opad = 64;  tile = bid - 52; }
    else               { src = g2w2; dst = d5; K = 35;   O = 35;  Kpad = 64;   Opad = 64;  tile = 0; }
    int ktiles = Kpad >> 6;
    int ot = tile / ktiles, kt = tile - ot * ktiles;
    int k0 = kt * 64, o0 = ot * 64;
    size_t LOFF = (size_t)Opad * Kpad;
    __shared__ float tl[64][68];
    int c = threadIdx.x & 63, rr = threadIdx.x >> 6;
    #pragma unroll
    for (int it = 0; it < 16; ++it) {
        int r = rr + it * 4;
        int kk = k0 + r, oo = o0 + c;
        tl[r][c] = (kk < K && oo < O) ? src[(size_t)kk * O + oo] : 0.f;
    }
    __syncthreads();
    #pragma unroll
    for (int it = 0; it < 16; ++it) {
        int r = rr + it * 4;
        float v = tl[c][r];
        __bf16 hi = (__bf16)v;
        float lo = v - (float)hi;
        size_t pos = (size_t)(o0 + r) * Kpad + k0 + c;
        dst[pos] = hi;
        dst[LOFF + pos] = (__bf16)lo;
    }
}

// ---------------------------------------------------------------------------
// MFMA conv1d, Cin=Cout=64. Output [n][t][64co] bf16.
// v3: K-loop is pure LDS+MFMA. Input staged once (padded stride 72,
// even/odd split for stride 2); weights staged per KCHUNK taps into LDS
// with padded rows (stride 72). Staging loops are constant-trip and fully
// unrolled -> independent loads in flight (MLP), no per-iter latency chain.
// IMODE: 0 = fp32 [ci][L] in (float4 + transpose), 1 = bf16 [t][64] in,
//        2 = bf16 [t][64] in with fused avgpool3/s2 from length-82 rows.
// ---------------------------------------------------------------------------
template<int K, int STRIDE, int PAD, bool DO_BN, int IMODE,
         int NPB, int TPN, int LIN, int LOUT, int KCHUNK>
__global__ __launch_bounds__(NPB * TPN * 64) void conv_mfma(
    const void* __restrict__ xin, const __bf16* __restrict__ wT,
    const float* __restrict__ bias,
    const float* __restrict__ bn_g, const float* __restrict__ bn_b,
    const float* __restrict__ bn_m, const float* __restrict__ bn_v,
    __bf16* __restrict__ y)
{
    constexpr int THREADS = NPB * TPN * 64;
    constexpr int TBLK  = TPN * 48;
    constexpr int VSPAN = STRIDE * (TBLK - 1) + K;
    constexpr int NBUF  = (STRIDE == 2) ? 2 : 1;
    constexpr int ROWS  = (VSPAN + NBUF - 1) / NBUF;
    __shared__ __align__(16) __bf16 sx[NPB * NBUF * ROWS * 72];
    __shared__ __align__(16) __bf16 sw[KCHUNK * 64 * 72];

    const int tid = threadIdx.x;
    const int nb  = blockIdx.x * NPB;

    // ---- input staging ----
    if constexpr (IMODE == 0) {
        // fp32 [ci][LIN] -> bf16 [v(parity-split)][ci]; NPB==1 assumed.
        const float* xg = (const float*)xin + (size_t)nb * 64 * LIN;
        // zero pad rows: v in [0,PAD) and [LIN+PAD, VSPAN)
        constexpr int NZROWS = PAD + (VSPAN - LIN - PAD);
        if (tid < NZROWS * 64) {
            int zr = tid >> 6;
            int v = (zr < PAD) ? zr : (LIN + PAD + zr - PAD);
            sx[((v & (NBUF - 1)) * ROWS + (v >> (NBUF - 1))) * 72 + (tid & 63)] = (__bf16)0.f;
        }
        constexpr int J4 = LIN / 4;          // 100
        constexpr int NCH = 64 * J4;         // 6400
        constexpr int ITER = NCH / THREADS;  // 25
        #pragma unroll
        for (int it = 0; it < ITER; ++it) {
            int idx = it * THREADS + tid;
            int ci = idx / J4, j = idx - ci * J4;
            float4 f = *(const float4*)(xg + (size_t)ci * LIN + 4 * j);
            #pragma unroll
            for (int e = 0; e < 4; ++e) {
                int v = 4 * j + e + PAD;
                sx[((v & (NBUF - 1)) * ROWS + (v >> (NBUF - 1))) * 72 + ci] =
                    (__bf16)((e == 0) ? f.x : (e == 1) ? f.y : (e == 2) ? f.z : f.w);
            }
        }
    } else {
        const __bf16* xg = (const __bf16*)xin;
        constexpr int NSTG = NPB * VSPAN * 8;
        constexpr int ITER = (NSTG + THREADS - 1) / THREADS;
        #pragma unroll
        for (int it = 0; it < ITER; ++it) {
            int idx = it * THREADS + tid;
            if (idx < NSTG) {
                int n_l = idx / (VSPAN * 8);
                int r   = idx - n_l * (VSPAN * 8);
                int v = r >> 3, c8 = (r & 7) * 8;
                int buf = (STRIDE == 2) ? (v & 1) : 0;
                int row = (STRIDE == 2) ? (v >> 1) : v;
                __bf16* dst = sx + ((size_t)(n_l * NBUF + buf) * ROWS + row) * 72 + c8;
                if constexpr (IMODE == 1) {
                    if (v < LIN) {
                        const __bf16* src = xg + (((size_t)(nb + n_l) * LIN + v) * 64 + c8);
                        *(uint4*)dst = *(const uint4*)src;
                    } else {
                        #pragma unroll
                        for (int e = 0; e < 8; ++e) dst[e] = (__bf16)0.f;
                    }
                } else {
                    if (v < LIN) {
                        const __bf16* s0 = xg + (((size_t)(nb + n_l) * 82 + 2 * v) * 64 + c8);
                        #pragma unroll
                        for (int e = 0; e < 8; ++e)
                            dst[e] = (__bf16)(((float)s0[e] + (float)s0[64 + e] +
                                               (float)s0[128 + e]) * (1.f / 3.f));
                    } else {
                        #pragma unroll
                        for (int e = 0; e < 8; ++e) dst[e] = (__bf16)0.f;
                    }
                }
            }
        }
    }

    const int wave = tid >> 6, lane = tid & 63;
    const int n_l  = wave / TPN, tile = wave - n_l * TPN;
    const int m    = lane & 15, quad = lane >> 4;
    const __bf16* sxn = sx + (size_t)n_l * NBUF * ROWS * 72;

    f32x4 acc[3][4];
    #pragma unroll
    for (int mi = 0; mi < 3; ++mi)
        #pragma unroll
        for (int nj = 0; nj < 4; ++nj)
            acc[mi][nj] = (f32x4){0.f, 0.f, 0.f, 0.f};

    for (int kb = 0; kb < K; kb += KCHUNK) {
        if (kb) __syncthreads();
        // stage KCHUNK taps of weights: sw[(tap*64+co) padded row 72]
        constexpr int WITER = KCHUNK * 64 * 8 / THREADS;
        #pragma unroll
        for (int it = 0; it < WITER; ++it) {
            int idx = it * THREADS + tid;
            int r = idx >> 3, p = idx & 7;
            *(uint4*)(sw + (size_t)r * 72 + p * 8) =
                *(const uint4*)(wT + (size_t)(kb + (r >> 6)) * 4096 + (r & 63) * 64 + p * 8);
        }
        __syncthreads();

        #pragma unroll
        for (int kp2 = 0; kp2 < KCHUNK; ++kp2) {
            const int kp = kb + kp2;
            const int buf    = (STRIDE == 2) ? (kp & 1) : 0;
            const int rowoff = (STRIDE == 2) ? (kp >> 1) : kp;
            const __bf16* abase = sxn + ((size_t)buf * ROWS + tile * 48 + m + rowoff) * 72;
            const __bf16* bbase = sw + (size_t)(kp2 * 64 + m) * 72;
            #pragma unroll
            for (int s = 0; s < 2; ++s) {
                bf16x8 af[3], bfr[4];
                #pragma unroll
                for (int mi = 0; mi < 3; ++mi)
                    af[mi] = *(const bf16x8*)(abase + mi * (16 * 72) + s * 32 + quad * 8);
                #pragma unroll
                for (int nj = 0; nj < 4; ++nj)
                    bfr[nj] = *(const bf16x8*)(bbase + nj * (16 * 72) + s * 32 + quad * 8);
                #pragma unroll
                for (int mi = 0; mi < 3; ++mi)
                    #pragma unroll
                    for (int nj = 0; nj < 4; ++nj)
                        acc[mi][nj] = __builtin_amdgcn_mfma_f32_16x16x32_bf16(
                            af[mi], bfr[nj], acc[mi][nj], 0, 0, 0);
            }
        }
    }

    #pragma unroll
    for (int nj = 0; nj < 4; ++nj) {
        const int co = nj * 16 + m;
        const float bi = bias[co];
        float scale = 1.f, shift = 0.f;
        if constexpr (DO_BN) {
            float inv = bn_g[co] / sqrtf(bn_v[co] + 1e-5f);
            scale = inv; shift = bn_b[co] - bn_m[co] * inv;
        }
        #pragma unroll
        for (int mi = 0; mi < 3; ++mi) {
            #pragma unroll
            for (int r = 0; r < 4; ++r) {
                int t = tile * 48 + mi * 16 + quad * 4 + r;
                if (t < LOUT) {
                    float v = acc[mi][nj][r] + bi;
                    v = elu_f(v);
                    if constexpr (DO_BN) v = v * scale + shift;
                    y[((size_t)(nb + n_l) * LOUT + t) * 64 + co] = (__bf16)v;
                }
            }
        }
    }
}

// ---------------------------------------------------------------------------
// Attention pooling over crop dim. One block per (b,c). h: [512][35][64] bf16.
// ---------------------------------------------------------------------------
__global__ __launch_bounds__(256) void attn_pool_k(
    const __bf16* __restrict__ h, const float* __restrict__ W,
    const float* __restrict__ ab, const float* __restrict__ u,
    float* __restrict__ out)
{
    const int b = blockIdx.x >> 6;
    const int c = blockIdx.x & 63;
    __shared__ float sh[16 * 35];
    __shared__ float slog[16];
    __shared__ float sred[4];
    __shared__ float salpha[16];
    const int tid = threadIdx.x;
    for (int idx = tid; idx < 16 * 35; idx += 256) {
        int s = idx / 35, hh = idx - s * 35;
        sh[idx] = (float)h[((size_t)(b * 16 + s) * 35 + hh) * 64 + c];
    }
    __syncthreads();
    float Wc[35];
    #pragma unroll
    for (int k = 0; k < 35; ++k) Wc[k] = W[k * 256 + tid];
    const float myb = ab[tid], myu = u[tid];
    for (int s = 0; s < 16; ++s) {
        float dot = myb;
        #pragma unroll
        for (int k = 0; k < 35; ++k) dot = fmaf(sh[s * 35 + k], Wc[k], dot);
        float val = tanhf(dot) * myu;
        #pragma unroll
        for (int off = 32; off > 0; off >>= 1) val += __shfl_down(val, off, 64);
        if ((tid & 63) == 0) sred[tid >> 6] = val;
        __syncthreads();
        if (tid == 0) slog[s] = sred[0] + sred[1] + sred[2] + sred[3];
        __syncthreads();
    }
    if (tid == 0) {
        float mx = slog[0];
        for (int s = 1; s < 16; ++s) mx = fmaxf(mx, slog[s]);
        float sum = 0.f, e[16];
        for (int s = 0; s < 16; ++s) { e[s] = expf(slog[s] - mx); sum += e[s]; }
        float inv = 1.f / sum;
        for (int s = 0; s < 16; ++s) salpha[s] = e[s] * inv;
    }
    __syncthreads();
    if (tid < 35) {
        float acc = 0.f;
        for (int s = 0; s < 16; ++s) acc = fmaf(sh[s * 35 + tid], salpha[s], acc);
        out[((size_t)(b * 64 + c)) * 35 + tid] = elu_f(acc);
    }
}

// ---------------------------------------------------------------------------
// Fused GIN stack, split-bf16 (hi/lo) precision (3 MFMA per logical product).
// ---------------------------------------------------------------------------
#define APLANE (64 * 264)

__device__ __forceinline__ void gin_gemm_dev(
    const __bf16* As,                 // hi plane; lo at As+APLANE
    const __bf16* __restrict__ Wg, int Kpad, int wlo, int Kout,
    const float* __restrict__ bias,
    int mode,                 // 0: relu->A   1: relu, +colsum ->A   2: raw->global
    __bf16* Ad, float* __restrict__ outg)
{
    const int lane = threadIdx.x & 63;
    const int wave_o0 = (threadIdx.x >> 6) * 64;
    if (wave_o0 >= ((Kout + 63) & ~63)) return;
    const int m = lane & 15, quad = lane >> 4;

    f32x4 acc[4][4];
    #pragma unroll
    for (int mi = 0; mi < 4; ++mi)
        #pragma unroll
        for (int nj = 0; nj < 4; ++nj)
            acc[mi][nj] = (f32x4){0.f, 0.f, 0.f, 0.f};

    for (int k0 = 0; k0 < Kpad; k0 += 32) {
        bf16x8 ah[4], al[4], bh[4], bl[4];
        #pragma unroll
        for (int mi = 0; mi < 4; ++mi) {
            const __bf16* ap = As + (size_t)(mi * 16 + m) * 264 + k0 + quad * 8;
            ah[mi] = *(const bf16x8*)ap;
            al[mi] = *(const bf16x8*)(ap + APLANE);
        }
        #pragma unroll
        for (int nj = 0; nj < 4; ++nj) {
            const __bf16* wp = Wg + (size_t)(wave_o0 + nj * 16 + m) * Kpad + k0 + quad * 8;
            bh[nj] = *(const bf16x8*)wp;
            bl[nj] = *(const bf16x8*)(wp + wlo);
        }
        #pragma unroll
        for (int mi = 0; mi < 4; ++mi)
            #pragma unroll
            for (int nj = 0; nj < 4; ++nj) {
                acc[mi][nj] = __builtin_amdgcn_mfma_f32_16x16x32_bf16(
                    al[mi], bh[nj], acc[mi][nj], 0, 0, 0);
                acc[mi][nj] = __builtin_amdgcn_mfma_f32_16x16x32_bf16(
                    ah[mi], bl[nj], acc[mi][nj], 0, 0, 0);
                acc[mi][nj] = __builtin_amdgcn_mfma_f32_16x16x32_bf16(
                    ah[mi], bh[nj], acc[mi][nj], 0, 0, 0);
            }
    }

    #pragma unroll
    for (int nj = 0; nj < 4; ++nj) {
        const int o = wave_o0 + nj * 16 + m;
        const bool ovalid = (o < Kout);
        const float bi = ovalid ? bias[o] : 0.f;
        float v[4][4];
        #pragma unroll
        for (int mi = 0; mi < 4; ++mi)
            #pragma unroll
            for (int r = 0; r < 4; ++r)
                v[mi][r] = acc[mi][nj][r] + bi;
        if (mode == 2) {
            if (ovalid) {
                #pragma unroll
                for (int mi = 0; mi < 4; ++mi)
                    #pragma unroll
                    for (int r = 0; r < 4; ++r)
                        outg[(size_t)(mi * 16 + quad * 4 + r) * Kout + o] = v[mi][r];
            }
        } else {
            float s = 0.f;
            #pragma unroll
            for (int mi = 0; mi < 4; ++mi)
                #pragma unroll
                for (int r = 0; r < 4; ++r) {
                    float rv = ovalid ? fmaxf(v[mi][r], 0.f) : 0.f;
                    v[mi][r] = rv;
                    s += rv;
                }
            if (mode == 1) {
                s += __shfl_xor(s, 16, 64);
                s += __shfl_xor(s, 32, 64);
            } else {
                s = 0.f;
            }
            #pragma unroll
            for (int mi = 0; mi < 4; ++mi)
                #pragma unroll
                for (int r = 0; r < 4; ++r) {
                    float a = v[mi][r] + s;
                    __bf16 hi = (__bf16)a;
                    size_t pos = (size_t)(mi * 16 + quad * 4 + r) * 264 + o;
                    Ad[pos] = hi;
                    Ad[APLANE + pos] = (__bf16)(a - (float)hi);
                }
        }
    }
}

__global__ __launch_bounds__(256) void gin_fused(
    const float* __restrict__ ha,
    const __bf16* __restrict__ gW0a, const __bf16* __restrict__ gW0b,
    const __bf16* __restrict__ gW1a, const __bf16* __restrict__ gW1b,
    const __bf16* __restrict__ gW2a, const __bf16* __restrict__ gW2b,
    const float* __restrict__ b0a, const float* __restrict__ b0b,
    const float* __restrict__ b1a, const float* __restrict__ b1b,
    const float* __restrict__ b2a, const float* __restrict__ b2b,
    float* __restrict__ H3)
{
    const int b = blockIdx.x, tid = threadIdx.x;
    __shared__ __align__(16) __bf16 sA[2][2 * APLANE];
    __shared__ float sS[64];
    const float* hab = ha + (size_t)b * 2240;

    if (tid < 64) {
        float s = 0.f;
        if (tid < 35)
            for (int n = 0; n < 64; ++n) s += hab[n * 35 + tid];
        sS[tid] = s;
    }
    __syncthreads();
    for (int idx = tid; idx < 64 * 64; idx += 256) {
        int n = idx >> 6, k = idx & 63;
        float a = (k < 35) ? hab[n * 35 + k] + sS[k] : 0.f;
        __bf16 hi = (__bf16)a;
        sA[0][n * 264 + k] = hi;
        sA[0][APLANE + n * 264 + k] = (__bf16)(a - (float)hi);
    }
    __syncthreads();

    gin_gemm_dev(sA[0], gW0a, 64,  16384, 256, b0a, 0, sA[1], nullptr); __syncthreads();
    gin_gemm_dev(sA[1], gW0b, 256, 65536, 256, b0b, 1, sA[0], nullptr); __syncthreads();
    gin_gemm_dev(sA[0], gW1a, 256, 65536, 256, b1a, 0, sA[1], nullptr); __syncthreads();
    gin_gemm_dev(sA[1], gW1b, 256, 65536, 256, b1b, 1, sA[0], nullptr); __syncthreads();
    gin_gemm_dev(sA[0], gW2a, 256, 16384, 35,  b2a, 0, sA[1], nullptr); __syncthreads();
    gin_gemm_dev(sA[1], gW2b, 64,  4096,  35,  b2b, 2, nullptr, H3 + (size_t)b * 2240);
}

// ---------------------------------------------------------------------------
// Classifier layer 1, fp32 exact, split across outputs for parallelism.
// ---------------------------------------------------------------------------
__global__ __launch_bounds__(256) void cls1_split_k(
    const float* __restrict__ H3, const float* __restrict__ w1,
    const float* __restrict__ b1, float* __restrict__ s1g)
{
    __shared__ float sH[32 * 560];
    const int tid = threadIdx.x;
    const int o = blockIdx.x * 8 + (tid & 7);
    const int b = tid >> 3;
    float a0 = 0.f, a1 = 0.f, a2 = 0.f, a3 = 0.f;
    for (int kc = 0; kc < 2240; kc += 560) {
        for (int i = tid; i < 32 * 560; i += 256) {
            int bb = i / 560, kk = i - bb * 560;
            sH[bb * 560 + kk] = H3[(size_t)bb * 2240 + kc + kk];
        }
        __syncthreads();
        const float* hr = sH + b * 560;
        const float* wr = w1 + (size_t)kc * 256 + o;
        #pragma unroll 4
        for (int k = 0; k < 560; k += 4) {
            a0 = fmaf(hr[k],     wr[(size_t)k * 256],       a0);
            a1 = fmaf(hr[k + 1], wr[(size_t)(k + 1) * 256], a1);
            a2 = fmaf(hr[k + 2], wr[(size_t)(k + 2) * 256], a2);
            a3 = fmaf(hr[k + 3], wr[(size_t)(k + 3) * 256], a3);
        }
        __syncthreads();
    }
    s1g[(size_t)b * 256 + o] = elu_f(a0 + a1 + a2 + a3 + b1[o]);
}

// ---------------------------------------------------------------------------
// Classifier layers 2-4 (tiny, fp32 exact). One block per batch element.
// ---------------------------------------------------------------------------
__global__ __launch_bounds__(256) void cls234_k(
    const float* __restrict__ s1g,
    const float* __restrict__ w2, const float* __restrict__ b2,
    const float* __restrict__ w3, const float* __restrict__ b3,
    const float* __restrict__ w4, const float* __restrict__ b4,
    float* __restrict__ out)
{
    const int b = blockIdx.x, tid = threadIdx.x;
    __shared__ float s1[256];
    __shared__ float part[4][64];
    __shared__ float s2[64];
    __shared__ float s3[16];
    s1[tid] = s1g[(size_t)b * 256 + tid];
    __syncthreads();
    {
        int kg = tid >> 6, o = tid & 63;
        float acc = 0.f;
        for (int k = kg * 64; k < kg * 64 + 64; ++k)
            acc = fmaf(s1[k], w2[k * 64 + o], acc);
        part[kg][o] = acc;
    }
    __syncthreads();
    if (tid < 64) {
        float acc = part[0][tid] + part[1][tid] + part[2][tid] + part[3][tid] + b2[tid];
        s2[tid] = elu_f(acc);
    }
    __syncthreads();
    if (tid < 16) {
        float acc = b3[tid];
        for (int k = 0; k < 64; ++k) acc = fmaf(s2[k], w3[k * 16 + tid], acc);
        s3[tid] = elu_f(acc);
    }
    __syncthreads();
    if (tid < 2) {
        float acc = b4[tid];
        for (int k = 0; k < 16; ++k) acc = fmaf(s3[k], w4[k * 2 + tid], acc);
        out[b * 2 + tid] = acc;
    }
}

// ---------------------------------------------------------------------------
extern "C" void kernel_launch(void* const* d_in, const int* in_sizes, int n_in,
                              void* d_out, int out_size, void* d_ws, size_t ws_size,
                              hipStream_t stream)
{
    const float* x     = (const float*)d_in[0];
    const float* w1    = (const float*)d_in[1];
    const float* b1    = (const float*)d_in[2];
    const float* bn1_g = (const float*)d_in[3];
    const float* bn1_b = (const float*)d_in[4];
    const float* bn1_m = (const float*)d_in[5];
    const float* bn1_v = (const float*)d_in[6];
    const float* w2    = (const float*)d_in[7];
    const float* b2    = (const float*)d_in[8];
    const float* bn2_g = (const float*)d_in[9];
    const float* bn2_b = (const float*)d_in[10];
    const float* bn2_m = (const float*)d_in[11];
    const float* bn2_v = (const float*)d_in[12];
    const float* w3    = (const float*)d_in[13];
    const float* b3    = (const float*)d_in[14];
    const float* w4    = (const float*)d_in[15];
    const float* b4    = (const float*)d_in[16];
    const float* attn_w = (const float*)d_in[17];
    const float* attn_b = (const float*)d_in[18];
    const float* attn_u = (const float*)d_in[19];
    const float* g0_w1 = (const float*)d_in[20];
    const float* g0_b1 = (const float*)d_in[21];
    const float* g0_w2 = (const float*)d_in[22];
    const float* g0_b2 = (const float*)d_in[23];
    const float* g1_w1 = (const float*)d_in[24];
    const float* g1_b1 = (const float*)d_in[25];
    const float* g1_w2 = (const float*)d_in[26];
    const float* g1_b2 = (const float*)d_in[27];
    const float* g2_w1 = (const float*)d_in[28];
    const float* g2_b1 = (const float*)d_in[29];
    const float* g2_w2 = (const float*)d_in[30];
    const float* g2_b2 = (const float*)d_in[31];
    const float* c_w1  = (const float*)d_in[32];
    const float* c_b1  = (const float*)d_in[33];
    const float* c_w2  = (const float*)d_in[34];
    const float* c_b2  = (const float*)d_in[35];
    const float* c_w3  = (const float*)d_in[36];
    const float* c_b3  = (const float*)d_in[37];
    const float* c_w4  = (const float*)d_in[38];
    const float* c_b4  = (const float*)d_in[39];
    float* out = (float*)d_out;

    char* ws = (char*)d_ws;
    __bf16* wT1  = (__bf16*)(ws + 0);
    __bf16* wT2  = (__bf16*)(ws + 163840);
    __bf16* wT3  = (__bf16*)(ws + 327680);
    __bf16* wT4  = (__bf16*)(ws + 376832);
    __bf16* h1   = (__bf16*)(ws + 425984);     // [512][192][64]
    __bf16* h2   = (__bf16*)(ws + 13008896);   // [512][87][64]
    __bf16* h3   = (__bf16*)(ws + 18710528);   // [512][82][64]
    __bf16* h4   = (__bf16*)(ws + 24084480);   // [512][35][64]
    float*  ha   = (float*)(ws + 26378240);    // [32][64][35]
    __bf16* gW0a = (__bf16*)(ws + 26664960);   // hi+lo [256][64]   65536 B
    __bf16* gW0b = (__bf16*)(ws + 26730496);   // hi+lo [256][256] 262144 B
    __bf16* gW1a = (__bf16*)(ws + 26992640);
    __bf16* gW1b = (__bf16*)(ws + 27254784);
    __bf16* gW2a = (__bf16*)(ws + 27516928);   // hi+lo [64][256]   65536 B
    __bf16* gW2b = (__bf16*)(ws + 27582464);   // hi+lo [64][64]    16384 B
    float*  H3   = (float*)(ws + 27598848);    // [32][2240]
    float*  s1g  = (float*)(ws + 27885568);    // [32][256]

    prep_weights<<<dim3(832), dim3(256), 0, stream>>>(w1, w2, w3, w4, wT1, wT2, wT3, wT4);
    prep_tr<<<dim3(57), dim3(256), 0, stream>>>(g0_w1, g0_w2, g1_w1, g1_w2, g2_w1, g2_w2,
                                                gW0a, gW0b, gW1a, gW1b, gW2a, gW2b);

    // CNN stack: pure-LDS K-loops, chunked weight staging
    conv_mfma<20, 2, 1, true, 0, 1, 4, 400, 192, 10><<<dim3(512), dim3(256), 0, stream>>>(
        x, wT1, b1, bn1_g, bn1_b, bn1_m, bn1_v, h1);
    conv_mfma<20, 2, 0, true, 1, 2, 2, 192, 87, 10><<<dim3(256), dim3(256), 0, stream>>>(
        h1, wT2, b2, bn2_g, bn2_b, bn2_m, bn2_v, h2);
    conv_mfma<6, 1, 0, false, 1, 1, 2, 87, 82, 6><<<dim3(512), dim3(128), 0, stream>>>(
        h2, wT3, b3, nullptr, nullptr, nullptr, nullptr, h3);
    conv_mfma<6, 1, 0, false, 2, 2, 1, 40, 35, 6><<<dim3(256), dim3(128), 0, stream>>>(
        h3, wT4, b4, nullptr, nullptr, nullptr, nullptr, h4);

    attn_pool_k<<<dim3(2048), dim3(256), 0, stream>>>(h4, attn_w, attn_b, attn_u, ha);

    gin_fused<<<dim3(32), dim3(256), 0, stream>>>(
        ha, gW0a, gW0b, gW1a, gW1b, gW2a, gW2b,
        g0_b1, g0_b2, g1_b1, g1_b2, g2_b1, g2_b2, H3);

    cls1_split_k<<<dim3(32), dim3(256), 0, stream>>>(H3, c_w1, c_b1, s1g);
    cls234_k<<<dim3(32), dim3(256), 0, stream>>>(s1g, c_w2, c_b2, c_w3, c_b3, c_w4, c_b4, out);
}

// Round 7
// 343.818 us; speedup vs baseline: 2.9234x; 1.1982x over previous
//
#include <hip/hip_runtime.h>
#include <math.h>

typedef __attribute__((ext_vector_type(8))) __bf16 bf16x8;
typedef __attribute__((ext_vector_type(4))) float f32x4;

__device__ __forceinline__ float elu_f(float v) {
    return v > 0.f ? v : (expf(v) - 1.f);
}

// ---------------------------------------------------------------------------
// Conv weight reorder: w[co][ci][K] fp32 -> wT[k][co][ci] bf16 (all 4 convs).
// ---------------------------------------------------------------------------
__global__ __launch_bounds__(256) void prep_weights(
    const float* __restrict__ w1, const float* __restrict__ w2,
    const float* __restrict__ w3, const float* __restrict__ w4,
    __bf16* __restrict__ t1, __bf16* __restrict__ t2,
    __bf16* __restrict__ t3, __bf16* __restrict__ t4)
{
    int idx = blockIdx.x * 256 + threadIdx.x;
    if (idx < 81920) {
        int k = idx / 4096, r = idx - k * 4096, co = r >> 6, ci = r & 63;
        t1[idx] = (__bf16)w1[(co * 64 + ci) * 20 + k];
    } else if (idx < 163840) {
        int j = idx - 81920;
        int k = j / 4096, r = j - k * 4096, co = r >> 6, ci = r & 63;
        t2[j] = (__bf16)w2[(co * 64 + ci) * 20 + k];
    } else if (idx < 188416) {
        int j = idx - 163840;
        int k = j / 4096, r = j - k * 4096, co = r >> 6, ci = r & 63;
        t3[j] = (__bf16)w3[(co * 64 + ci) * 6 + k];
    } else if (idx < 212992) {
        int j = idx - 188416;
        int k = j / 4096, r = j - k * 4096, co = r >> 6, ci = r & 63;
        t4[j] = (__bf16)w4[(co * 64 + ci) * 6 + k];
    }
}

// ---------------------------------------------------------------------------
// Tiled transpose+convert with hi/lo split for GIN weights. 57 blocks.
// ---------------------------------------------------------------------------
__global__ __launch_bounds__(256) void prep_tr(
    const float* __restrict__ g0w1, const float* __restrict__ g0w2,
    const float* __restrict__ g1w1, const float* __restrict__ g1w2,
    const float* __restrict__ g2w1, const float* __restrict__ g2w2,
    __bf16* __restrict__ d0, __bf16* __restrict__ d1, __bf16* __restrict__ d2,
    __bf16* __restrict__ d3, __bf16* __restrict__ d4, __bf16* __restrict__ d5)
{
    int bid = blockIdx.x;
    const float* src; __bf16* dst; int K, O, Kpad, Opad, tile;
    if (bid < 4)       { src = g0w1; dst = d0; K = 35;   O = 256; Kpad = 64;   Opad = 256; tile = bid; }
    else if (bid < 20) { src = g0w2; dst = d1; K = 256;  O = 256; Kpad = 256;  Opad = 256; tile = bid - 4; }
    else if (bid < 36) { src = g1w1; dst = d2; K = 256;  O = 256; Kpad = 256;  Opad = 256; tile = bid - 20; }
    else if (bid < 52) { src = g1w2; dst = d3; K = 256;  O = 256; Kpad = 256;  Opad = 256; tile = bid - 36; }
    else if (bid < 56) { src = g2w1; dst = d4; K = 256;  O = 35;  Kpad = 256;  Opad = 64;  tile = bid - 52; }
    else               { src = g2w2; dst = d5; K = 35;   O = 35;  Kpad = 64;   Opad = 64;  tile = 0; }
    int ktiles = Kpad >> 6;
    int ot = tile / ktiles, kt = tile - ot * ktiles;
    int k0 = kt * 64, o0 = ot * 64;
    size_t LOFF = (size_t)Opad * Kpad;
    __shared__ float tl[64][68];
    int c = threadIdx.x & 63, rr = threadIdx.x >> 6;
    #pragma unroll
    for (int it = 0; it < 16; ++it) {
        int r = rr + it * 4;
        int kk = k0 + r, oo = o0 + c;
        tl[r][c] = (kk < K && oo < O) ? src[(size_t)kk * O + oo] : 0.f;
    }
    __syncthreads();
    #pragma unroll
    for (int it = 0; it < 16; ++it) {
        int r = rr + it * 4;
        float v = tl[c][r];
        __bf16 hi = (__bf16)v;
        float lo = v - (float)hi;
        size_t pos = (size_t)(o0 + r) * Kpad + k0 + c;
        dst[pos] = hi;
        dst[LOFF + pos] = (__bf16)lo;
    }
}

// ---------------------------------------------------------------------------
// MFMA conv1d, Cin=Cout=64. Output [n][t][64co] bf16. Pure-LDS K-loop,
// chunked weight staging, constant-trip unrolled staging loops.
// ---------------------------------------------------------------------------
template<int K, int STRIDE, int PAD, bool DO_BN, int IMODE,
         int NPB, int TPN, int LIN, int LOUT, int KCHUNK>
__global__ __launch_bounds__(NPB * TPN * 64) void conv_mfma(
    const void* __restrict__ xin, const __bf16* __restrict__ wT,
    const float* __restrict__ bias,
    const float* __restrict__ bn_g, const float* __restrict__ bn_b,
    const float* __restrict__ bn_m, const float* __restrict__ bn_v,
    __bf16* __restrict__ y)
{
    constexpr int THREADS = NPB * TPN * 64;
    constexpr int TBLK  = TPN * 48;
    constexpr int VSPAN = STRIDE * (TBLK - 1) + K;
    constexpr int NBUF  = (STRIDE == 2) ? 2 : 1;
    constexpr int ROWS  = (VSPAN + NBUF - 1) / NBUF;
    __shared__ __align__(16) __bf16 sx[NPB * NBUF * ROWS * 72];
    __shared__ __align__(16) __bf16 sw[KCHUNK * 64 * 72];

    const int tid = threadIdx.x;
    const int nb  = blockIdx.x * NPB;

    if constexpr (IMODE == 0) {
        const float* xg = (const float*)xin + (size_t)nb * 64 * LIN;
        constexpr int NZROWS = PAD + (VSPAN - LIN - PAD);
        if (tid < NZROWS * 64) {
            int zr = tid >> 6;
            int v = (zr < PAD) ? zr : (LIN + PAD + zr - PAD);
            sx[((v & (NBUF - 1)) * ROWS + (v >> (NBUF - 1))) * 72 + (tid & 63)] = (__bf16)0.f;
        }
        constexpr int J4 = LIN / 4;
        constexpr int NCH = 64 * J4;
        constexpr int ITER = NCH / THREADS;
        #pragma unroll
        for (int it = 0; it < ITER; ++it) {
            int idx = it * THREADS + tid;
            int ci = idx / J4, j = idx - ci * J4;
            float4 f = *(const float4*)(xg + (size_t)ci * LIN + 4 * j);
            #pragma unroll
            for (int e = 0; e < 4; ++e) {
                int v = 4 * j + e + PAD;
                sx[((v & (NBUF - 1)) * ROWS + (v >> (NBUF - 1))) * 72 + ci] =
                    (__bf16)((e == 0) ? f.x : (e == 1) ? f.y : (e == 2) ? f.z : f.w);
            }
        }
    } else {
        const __bf16* xg = (const __bf16*)xin;
        constexpr int NSTG = NPB * VSPAN * 8;
        constexpr int ITER = (NSTG + THREADS - 1) / THREADS;
        #pragma unroll
        for (int it = 0; it < ITER; ++it) {
            int idx = it * THREADS + tid;
            if (idx < NSTG) {
                int n_l = idx / (VSPAN * 8);
                int r   = idx - n_l * (VSPAN * 8);
                int v = r >> 3, c8 = (r & 7) * 8;
                int buf = (STRIDE == 2) ? (v & 1) : 0;
                int row = (STRIDE == 2) ? (v >> 1) : v;
                __bf16* dst = sx + ((size_t)(n_l * NBUF + buf) * ROWS + row) * 72 + c8;
                if constexpr (IMODE == 1) {
                    if (v < LIN) {
                        const __bf16* src = xg + (((size_t)(nb + n_l) * LIN + v) * 64 + c8);
                        *(uint4*)dst = *(const uint4*)src;
                    } else {
                        #pragma unroll
                        for (int e = 0; e < 8; ++e) dst[e] = (__bf16)0.f;
                    }
                } else {
                    if (v < LIN) {
                        const __bf16* s0 = xg + (((size_t)(nb + n_l) * 82 + 2 * v) * 64 + c8);
                        #pragma unroll
                        for (int e = 0; e < 8; ++e)
                            dst[e] = (__bf16)(((float)s0[e] + (float)s0[64 + e] +
                                               (float)s0[128 + e]) * (1.f / 3.f));
                    } else {
                        #pragma unroll
                        for (int e = 0; e < 8; ++e) dst[e] = (__bf16)0.f;
                    }
                }
            }
        }
    }

    const int wave = tid >> 6, lane = tid & 63;
    const int n_l  = wave / TPN, tile = wave - n_l * TPN;
    const int m    = lane & 15, quad = lane >> 4;
    const __bf16* sxn = sx + (size_t)n_l * NBUF * ROWS * 72;

    f32x4 acc[3][4];
    #pragma unroll
    for (int mi = 0; mi < 3; ++mi)
        #pragma unroll
        for (int nj = 0; nj < 4; ++nj)
            acc[mi][nj] = (f32x4){0.f, 0.f, 0.f, 0.f};

    for (int kb = 0; kb < K; kb += KCHUNK) {
        if (kb) __syncthreads();
        constexpr int WITER = KCHUNK * 64 * 8 / THREADS;
        #pragma unroll
        for (int it = 0; it < WITER; ++it) {
            int idx = it * THREADS + tid;
            int r = idx >> 3, p = idx & 7;
            *(uint4*)(sw + (size_t)r * 72 + p * 8) =
                *(const uint4*)(wT + (size_t)(kb + (r >> 6)) * 4096 + (r & 63) * 64 + p * 8);
        }
        __syncthreads();

        #pragma unroll
        for (int kp2 = 0; kp2 < KCHUNK; ++kp2) {
            const int kp = kb + kp2;
            const int buf    = (STRIDE == 2) ? (kp & 1) : 0;
            const int rowoff = (STRIDE == 2) ? (kp >> 1) : kp;
            const __bf16* abase = sxn + ((size_t)buf * ROWS + tile * 48 + m + rowoff) * 72;
            const __bf16* bbase = sw + (size_t)(kp2 * 64 + m) * 72;
            #pragma unroll
            for (int s = 0; s < 2; ++s) {
                bf16x8 af[3], bfr[4];
                #pragma unroll
                for (int mi = 0; mi < 3; ++mi)
                    af[mi] = *(const bf16x8*)(abase + mi * (16 * 72) + s * 32 + quad * 8);
                #pragma unroll
                for (int nj = 0; nj < 4; ++nj)
                    bfr[nj] = *(const bf16x8*)(bbase + nj * (16 * 72) + s * 32 + quad * 8);
                #pragma unroll
                for (int mi = 0; mi < 3; ++mi)
                    #pragma unroll
                    for (int nj = 0; nj < 4; ++nj)
                        acc[mi][nj] = __builtin_amdgcn_mfma_f32_16x16x32_bf16(
                            af[mi], bfr[nj], acc[mi][nj], 0, 0, 0);
            }
        }
    }

    #pragma unroll
    for (int nj = 0; nj < 4; ++nj) {
        const int co = nj * 16 + m;
        const float bi = bias[co];
        float scale = 1.f, shift = 0.f;
        if constexpr (DO_BN) {
            float inv = bn_g[co] / sqrtf(bn_v[co] + 1e-5f);
            scale = inv; shift = bn_b[co] - bn_m[co] * inv;
        }
        #pragma unroll
        for (int mi = 0; mi < 3; ++mi) {
            #pragma unroll
            for (int r = 0; r < 4; ++r) {
                int t = tile * 48 + mi * 16 + quad * 4 + r;
                if (t < LOUT) {
                    float v = acc[mi][nj][r] + bi;
                    v = elu_f(v);
                    if constexpr (DO_BN) v = v * scale + shift;
                    y[((size_t)(nb + n_l) * LOUT + t) * 64 + co] = (__bf16)v;
                }
            }
        }
    }
}

// ---------------------------------------------------------------------------
// Attention pooling over crop dim. One block per (b,c). h: [512][35][64] bf16.
// ---------------------------------------------------------------------------
__global__ __launch_bounds__(256) void attn_pool_k(
    const __bf16* __restrict__ h, const float* __restrict__ W,
    const float* __restrict__ ab, const float* __restrict__ u,
    float* __restrict__ out)
{
    const int b = blockIdx.x >> 6;
    const int c = blockIdx.x & 63;
    __shared__ float sh[16 * 35];
    __shared__ float slog[16];
    __shared__ float sred[4];
    __shared__ float salpha[16];
    const int tid = threadIdx.x;
    for (int idx = tid; idx < 16 * 35; idx += 256) {
        int s = idx / 35, hh = idx - s * 35;
        sh[idx] = (float)h[((size_t)(b * 16 + s) * 35 + hh) * 64 + c];
    }
    __syncthreads();
    float Wc[35];
    #pragma unroll
    for (int k = 0; k < 35; ++k) Wc[k] = W[k * 256 + tid];
    const float myb = ab[tid], myu = u[tid];
    for (int s = 0; s < 16; ++s) {
        float dot = myb;
        #pragma unroll
        for (int k = 0; k < 35; ++k) dot = fmaf(sh[s * 35 + k], Wc[k], dot);
        float val = tanhf(dot) * myu;
        #pragma unroll
        for (int off = 32; off > 0; off >>= 1) val += __shfl_down(val, off, 64);
        if ((tid & 63) == 0) sred[tid >> 6] = val;
        __syncthreads();
        if (tid == 0) slog[s] = sred[0] + sred[1] + sred[2] + sred[3];
        __syncthreads();
    }
    if (tid == 0) {
        float mx = slog[0];
        for (int s = 1; s < 16; ++s) mx = fmaxf(mx, slog[s]);
        float sum = 0.f, e[16];
        for (int s = 0; s < 16; ++s) { e[s] = expf(slog[s] - mx); sum += e[s]; }
        float inv = 1.f / sum;
        for (int s = 0; s < 16; ++s) salpha[s] = e[s] * inv;
    }
    __syncthreads();
    if (tid < 35) {
        float acc = 0.f;
        for (int s = 0; s < 16; ++s) acc = fmaf(sh[s * 35 + tid], salpha[s], acc);
        out[((size_t)(b * 64 + c)) * 35 + tid] = elu_f(acc);
    }
}

// ---------------------------------------------------------------------------
// Fused GIN stack, split-bf16 (hi/lo) precision (3 MFMA per logical product).
// ---------------------------------------------------------------------------
#define APLANE (64 * 264)

__device__ __forceinline__ void gin_gemm_dev(
    const __bf16* As,                 // hi plane; lo at As+APLANE
    const __bf16* __restrict__ Wg, int Kpad, int wlo, int Kout,
    const float* __restrict__ bias,
    int mode,                 // 0: relu->A   1: relu, +colsum ->A   2: raw->global
    __bf16* Ad, float* __restrict__ outg)
{
    const int lane = threadIdx.x & 63;
    const int wave_o0 = (threadIdx.x >> 6) * 64;
    if (wave_o0 >= ((Kout + 63) & ~63)) return;
    const int m = lane & 15, quad = lane >> 4;

    f32x4 acc[4][4];
    #pragma unroll
    for (int mi = 0; mi < 4; ++mi)
        #pragma unroll
        for (int nj = 0; nj < 4; ++nj)
            acc[mi][nj] = (f32x4){0.f, 0.f, 0.f, 0.f};

    for (int k0 = 0; k0 < Kpad; k0 += 32) {
        bf16x8 ah[4], al[4], bh[4], bl[4];
        #pragma unroll
        for (int mi = 0; mi < 4; ++mi) {
            const __bf16* ap = As + (size_t)(mi * 16 + m) * 264 + k0 + quad * 8;
            ah[mi] = *(const bf16x8*)ap;
            al[mi] = *(const bf16x8*)(ap + APLANE);
        }
        #pragma unroll
        for (int nj = 0; nj < 4; ++nj) {
            const __bf16* wp = Wg + (size_t)(wave_o0 + nj * 16 + m) * Kpad + k0 + quad * 8;
            bh[nj] = *(const bf16x8*)wp;
            bl[nj] = *(const bf16x8*)(wp + wlo);
        }
        #pragma unroll
        for (int mi = 0; mi < 4; ++mi)
            #pragma unroll
            for (int nj = 0; nj < 4; ++nj) {
                acc[mi][nj] = __builtin_amdgcn_mfma_f32_16x16x32_bf16(
                    al[mi], bh[nj], acc[mi][nj], 0, 0, 0);
                acc[mi][nj] = __builtin_amdgcn_mfma_f32_16x16x32_bf16(
                    ah[mi], bl[nj], acc[mi][nj], 0, 0, 0);
                acc[mi][nj] = __builtin_amdgcn_mfma_f32_16x16x32_bf16(
                    ah[mi], bh[nj], acc[mi][nj], 0, 0, 0);
            }
    }

    #pragma unroll
    for (int nj = 0; nj < 4; ++nj) {
        const int o = wave_o0 + nj * 16 + m;
        const bool ovalid = (o < Kout);
        const float bi = ovalid ? bias[o] : 0.f;
        float v[4][4];
        #pragma unroll
        for (int mi = 0; mi < 4; ++mi)
            #pragma unroll
            for (int r = 0; r < 4; ++r)
                v[mi][r] = acc[mi][nj][r] + bi;
        if (mode == 2) {
            if (ovalid) {
                #pragma unroll
                for (int mi = 0; mi < 4; ++mi)
                    #pragma unroll
                    for (int r = 0; r < 4; ++r)
                        outg[(size_t)(mi * 16 + quad * 4 + r) * Kout + o] = v[mi][r];
            }
        } else {
            float s = 0.f;
            #pragma unroll
            for (int mi = 0; mi < 4; ++mi)
                #pragma unroll
                for (int r = 0; r < 4; ++r) {
                    float rv = ovalid ? fmaxf(v[mi][r], 0.f) : 0.f;
                    v[mi][r] = rv;
                    s += rv;
                }
            if (mode == 1) {
                s += __shfl_xor(s, 16, 64);
                s += __shfl_xor(s, 32, 64);
            } else {
                s = 0.f;
            }
            #pragma unroll
            for (int mi = 0; mi < 4; ++mi)
                #pragma unroll
                for (int r = 0; r < 4; ++r) {
                    float a = v[mi][r] + s;
                    __bf16 hi = (__bf16)a;
                    size_t pos = (size_t)(mi * 16 + quad * 4 + r) * 264 + o;
                    Ad[pos] = hi;
                    Ad[APLANE + pos] = (__bf16)(a - (float)hi);
                }
        }
    }
}

__global__ __launch_bounds__(256) void gin_fused(
    const float* __restrict__ ha,
    const __bf16* __restrict__ gW0a, const __bf16* __restrict__ gW0b,
    const __bf16* __restrict__ gW1a, const __bf16* __restrict__ gW1b,
    const __bf16* __restrict__ gW2a, const __bf16* __restrict__ gW2b,
    const float* __restrict__ b0a, const float* __restrict__ b0b,
    const float* __restrict__ b1a, const float* __restrict__ b1b,
    const float* __restrict__ b2a, const float* __restrict__ b2b,
    float* __restrict__ H3)
{
    const int b = blockIdx.x, tid = threadIdx.x;
    __shared__ __align__(16) __bf16 sA[2][2 * APLANE];
    __shared__ float sS[64];
    const float* hab = ha + (size_t)b * 2240;

    if (tid < 64) {
        float s = 0.f;
        if (tid < 35)
            for (int n = 0; n < 64; ++n) s += hab[n * 35 + tid];
        sS[tid] = s;
    }
    __syncthreads();
    for (int idx = tid; idx < 64 * 64; idx += 256) {
        int n = idx >> 6, k = idx & 63;
        float a = (k < 35) ? hab[n * 35 + k] + sS[k] : 0.f;
        __bf16 hi = (__bf16)a;
        sA[0][n * 264 + k] = hi;
        sA[0][APLANE + n * 264 + k] = (__bf16)(a - (float)hi);
    }
    __syncthreads();

    gin_gemm_dev(sA[0], gW0a, 64,  16384, 256, b0a, 0, sA[1], nullptr); __syncthreads();
    gin_gemm_dev(sA[1], gW0b, 256, 65536, 256, b0b, 1, sA[0], nullptr); __syncthreads();
    gin_gemm_dev(sA[0], gW1a, 256, 65536, 256, b1a, 0, sA[1], nullptr); __syncthreads();
    gin_gemm_dev(sA[1], gW1b, 256, 65536, 256, b1b, 1, sA[0], nullptr); __syncthreads();
    gin_gemm_dev(sA[0], gW2a, 256, 16384, 35,  b2a, 0, sA[1], nullptr); __syncthreads();
    gin_gemm_dev(sA[1], gW2b, 64,  4096,  35,  b2b, 2, nullptr, H3 + (size_t)b * 2240);
}

// ---------------------------------------------------------------------------
// Classifier layer 1, fp32, K-split for parallelism: grid (b=32, kc=16).
// Each block: 140-long K-chunk; wave w covers outputs [w*64, w*64+64),
// lane <-> o (coalesced w1 reads). Partials to s1p[kc][b][o].
// ---------------------------------------------------------------------------
__global__ __launch_bounds__(256) void cls1_part_k(
    const float* __restrict__ H3, const float* __restrict__ w1,
    float* __restrict__ s1p)
{
    const int b  = blockIdx.x;
    const int kc = blockIdx.y;
    const int k0 = kc * 140;
    __shared__ float sH[140];
    const int tid = threadIdx.x;
    if (tid < 140) sH[tid] = H3[(size_t)b * 2240 + k0 + tid];
    __syncthreads();
    const int o = (tid >> 6) * 64 + (tid & 63);
    float a0 = 0.f, a1 = 0.f, a2 = 0.f, a3 = 0.f;
    const float* wr = w1 + (size_t)k0 * 256 + o;
    #pragma unroll
    for (int k = 0; k < 140; k += 4) {
        a0 = fmaf(sH[k],     wr[(size_t)k * 256],       a0);
        a1 = fmaf(sH[k + 1], wr[(size_t)(k + 1) * 256], a1);
        a2 = fmaf(sH[k + 2], wr[(size_t)(k + 2) * 256], a2);
        a3 = fmaf(sH[k + 3], wr[(size_t)(k + 3) * 256], a3);
    }
    s1p[((size_t)kc * 32 + b) * 256 + o] = a0 + a1 + a2 + a3;
}

// ---------------------------------------------------------------------------
// Classifier: reduce K-split partials (+bias, ELU), then layers 2-4 (fp32).
// One block per batch element.
// ---------------------------------------------------------------------------
__global__ __launch_bounds__(256) void cls234_k(
    const float* __restrict__ s1p, const float* __restrict__ b1,
    const float* __restrict__ w2, const float* __restrict__ b2,
    const float* __restrict__ w3, const float* __restrict__ b3,
    const float* __restrict__ w4, const float* __restrict__ b4,
    float* __restrict__ out)
{
    const int b = blockIdx.x, tid = threadIdx.x;
    __shared__ float s1[256];
    __shared__ float part[4][64];
    __shared__ float s2[64];
    __shared__ float s3[16];
    {
        float acc = b1[tid];
        #pragma unroll
        for (int kc = 0; kc < 16; ++kc)
            acc += s1p[((size_t)kc * 32 + b) * 256 + tid];
        s1[tid] = elu_f(acc);
    }
    __syncthreads();
    {
        int kg = tid >> 6, o = tid & 63;
        float acc = 0.f;
        for (int k = kg * 64; k < kg * 64 + 64; ++k)
            acc = fmaf(s1[k], w2[k * 64 + o], acc);
        part[kg][o] = acc;
    }
    __syncthreads();
    if (tid < 64) {
        float acc = part[0][tid] + part[1][tid] + part[2][tid] + part[3][tid] + b2[tid];
        s2[tid] = elu_f(acc);
    }
    __syncthreads();
    if (tid < 16) {
        float acc = b3[tid];
        for (int k = 0; k < 64; ++k) acc = fmaf(s2[k], w3[k * 16 + tid], acc);
        s3[tid] = elu_f(acc);
    }
    __syncthreads();
    if (tid < 2) {
        float acc = b4[tid];
        for (int k = 0; k < 16; ++k) acc = fmaf(s3[k], w4[k * 2 + tid], acc);
        out[b * 2 + tid] = acc;
    }
}

// ---------------------------------------------------------------------------
extern "C" void kernel_launch(void* const* d_in, const int* in_sizes, int n_in,
                              void* d_out, int out_size, void* d_ws, size_t ws_size,
                              hipStream_t stream)
{
    const float* x     = (const float*)d_in[0];
    const float* w1    = (const float*)d_in[1];
    const float* b1    = (const float*)d_in[2];
    const float* bn1_g = (const float*)d_in[3];
    const float* bn1_b = (const float*)d_in[4];
    const float* bn1_m = (const float*)d_in[5];
    const float* bn1_v = (const float*)d_in[6];
    const float* w2    = (const float*)d_in[7];
    const float* b2    = (const float*)d_in[8];
    const float* bn2_g = (const float*)d_in[9];
    const float* bn2_b = (const float*)d_in[10];
    const float* bn2_m = (const float*)d_in[11];
    const float* bn2_v = (const float*)d_in[12];
    const float* w3    = (const float*)d_in[13];
    const float* b3    = (const float*)d_in[14];
    const float* w4    = (const float*)d_in[15];
    const float* b4    = (const float*)d_in[16];
    const float* attn_w = (const float*)d_in[17];
    const float* attn_b = (const float*)d_in[18];
    const float* attn_u = (const float*)d_in[19];
    const float* g0_w1 = (const float*)d_in[20];
    const float* g0_b1 = (const float*)d_in[21];
    const float* g0_w2 = (const float*)d_in[22];
    const float* g0_b2 = (const float*)d_in[23];
    const float* g1_w1 = (const float*)d_in[24];
    const float* g1_b1 = (const float*)d_in[25];
    const float* g1_w2 = (const float*)d_in[26];
    const float* g1_b2 = (const float*)d_in[27];
    const float* g2_w1 = (const float*)d_in[28];
    const float* g2_b1 = (const float*)d_in[29];
    const float* g2_w2 = (const float*)d_in[30];
    const float* g2_b2 = (const float*)d_in[31];
    const float* c_w1  = (const float*)d_in[32];
    const float* c_b1  = (const float*)d_in[33];
    const float* c_w2  = (const float*)d_in[34];
    const float* c_b2  = (const float*)d_in[35];
    const float* c_w3  = (const float*)d_in[36];
    const float* c_b3  = (const float*)d_in[37];
    const float* c_w4  = (const float*)d_in[38];
    const float* c_b4  = (const float*)d_in[39];
    float* out = (float*)d_out;

    char* ws = (char*)d_ws;
    __bf16* wT1  = (__bf16*)(ws + 0);
    __bf16* wT2  = (__bf16*)(ws + 163840);
    __bf16* wT3  = (__bf16*)(ws + 327680);
    __bf16* wT4  = (__bf16*)(ws + 376832);
    __bf16* h1   = (__bf16*)(ws + 425984);     // [512][192][64]
    __bf16* h2   = (__bf16*)(ws + 13008896);   // [512][87][64]
    __bf16* h3   = (__bf16*)(ws + 18710528);   // [512][82][64]
    __bf16* h4   = (__bf16*)(ws + 24084480);   // [512][35][64]
    float*  ha   = (float*)(ws + 26378240);    // [32][64][35]
    __bf16* gW0a = (__bf16*)(ws + 26664960);   // hi+lo [256][64]   65536 B
    __bf16* gW0b = (__bf16*)(ws + 26730496);   // hi+lo [256][256] 262144 B
    __bf16* gW1a = (__bf16*)(ws + 26992640);
    __bf16* gW1b = (__bf16*)(ws + 27254784);
    __bf16* gW2a = (__bf16*)(ws + 27516928);   // hi+lo [64][256]   65536 B
    __bf16* gW2b = (__bf16*)(ws + 27582464);   // hi+lo [64][64]    16384 B
    float*  H3   = (float*)(ws + 27598848);    // [32][2240]
    float*  s1p  = (float*)(ws + 27885568);    // [16][32][256] = 524288 B

    prep_weights<<<dim3(832), dim3(256), 0, stream>>>(w1, w2, w3, w4, wT1, wT2, wT3, wT4);
    prep_tr<<<dim3(57), dim3(256), 0, stream>>>(g0_w1, g0_w2, g1_w1, g1_w2, g2_w1, g2_w2,
                                                gW0a, gW0b, gW1a, gW1b, gW2a, gW2b);

    conv_mfma<20, 2, 1, true, 0, 1, 4, 400, 192, 10><<<dim3(512), dim3(256), 0, stream>>>(
        x, wT1, b1, bn1_g, bn1_b, bn1_m, bn1_v, h1);
    conv_mfma<20, 2, 0, true, 1, 2, 2, 192, 87, 10><<<dim3(256), dim3(256), 0, stream>>>(
        h1, wT2, b2, bn2_g, bn2_b, bn2_m, bn2_v, h2);
    conv_mfma<6, 1, 0, false, 1, 1, 2, 87, 82, 6><<<dim3(512), dim3(128), 0, stream>>>(
        h2, wT3, b3, nullptr, nullptr, nullptr, nullptr, h3);
    conv_mfma<6, 1, 0, false, 2, 2, 1, 40, 35, 6><<<dim3(256), dim3(128), 0, stream>>>(
        h3, wT4, b4, nullptr, nullptr, nullptr, nullptr, h4);

    attn_pool_k<<<dim3(2048), dim3(256), 0, stream>>>(h4, attn_w, attn_b, attn_u, ha);

    gin_fused<<<dim3(32), dim3(256), 0, stream>>>(
        ha, gW0a, gW0b, gW1a, gW1b, gW2a, gW2b,
        g0_b1, g0_b2, g1_b1, g1_b2, g2_b1, g2_b2, H3);

    cls1_part_k<<<dim3(32, 16), dim3(256), 0, stream>>>(H3, c_w1, s1p);
    cls234_k<<<dim3(32), dim3(256), 0, stream>>>(s1p, c_b1, c_w2, c_b2, c_w3, c_b3,
                                                 c_w4, c_b4, out);
}

// Round 8
// 339.311 us; speedup vs baseline: 2.9623x; 1.0133x over previous
//
#include <hip/hip_runtime.h>
#include <math.h>

typedef __attribute__((ext_vector_type(8))) __bf16 bf16x8;
typedef __attribute__((ext_vector_type(4))) float f32x4;

__device__ __forceinline__ float elu_f(float v) {
    return v > 0.f ? v : (expf(v) - 1.f);
}

// ---------------------------------------------------------------------------
// Conv weight reorder: w[co][ci][K] fp32 -> wT[k][co][ci] bf16 (all 4 convs).
// ---------------------------------------------------------------------------
__global__ __launch_bounds__(256) void prep_weights(
    const float* __restrict__ w1, const float* __restrict__ w2,
    const float* __restrict__ w3, const float* __restrict__ w4,
    __bf16* __restrict__ t1, __bf16* __restrict__ t2,
    __bf16* __restrict__ t3, __bf16* __restrict__ t4)
{
    int idx = blockIdx.x * 256 + threadIdx.x;
    if (idx < 81920) {
        int k = idx / 4096, r = idx - k * 4096, co = r >> 6, ci = r & 63;
        t1[idx] = (__bf16)w1[(co * 64 + ci) * 20 + k];
    } else if (idx < 163840) {
        int j = idx - 81920;
        int k = j / 4096, r = j - k * 4096, co = r >> 6, ci = r & 63;
        t2[j] = (__bf16)w2[(co * 64 + ci) * 20 + k];
    } else if (idx < 188416) {
        int j = idx - 163840;
        int k = j / 4096, r = j - k * 4096, co = r >> 6, ci = r & 63;
        t3[j] = (__bf16)w3[(co * 64 + ci) * 6 + k];
    } else if (idx < 212992) {
        int j = idx - 188416;
        int k = j / 4096, r = j - k * 4096, co = r >> 6, ci = r & 63;
        t4[j] = (__bf16)w4[(co * 64 + ci) * 6 + k];
    }
}

// ---------------------------------------------------------------------------
// Tiled transpose+convert with hi/lo split for GIN weights. 57 blocks.
// ---------------------------------------------------------------------------
__global__ __launch_bounds__(256) void prep_tr(
    const float* __restrict__ g0w1, const float* __restrict__ g0w2,
    const float* __restrict__ g1w1, const float* __restrict__ g1w2,
    const float* __restrict__ g2w1, const float* __restrict__ g2w2,
    __bf16* __restrict__ d0, __bf16* __restrict__ d1, __bf16* __restrict__ d2,
    __bf16* __restrict__ d3, __bf16* __restrict__ d4, __bf16* __restrict__ d5)
{
    int bid = blockIdx.x;
    const float* src; __bf16* dst; int K, O, Kpad, Opad, tile;
    if (bid < 4)       { src = g0w1; dst = d0; K = 35;   O = 256; Kpad = 64;   Opad = 256; tile = bid; }
    else if (bid < 20) { src = g0w2; dst = d1; K = 256;  O = 256; Kpad = 256;  Opad = 256; tile = bid - 4; }
    else if (bid < 36) { src = g1w1; dst = d2; K = 256;  O = 256; Kpad = 256;  Opad = 256; tile = bid - 20; }
    else if (bid < 52) { src = g1w2; dst = d3; K = 256;  O = 256; Kpad = 256;  Opad = 256; tile = bid - 36; }
    else if (bid < 56) { src = g2w1; dst = d4; K = 256;  O = 35;  Kpad = 256;  Opad = 64;  tile = bid - 52; }
    else               { src = g2w2; dst = d5; K = 35;   O = 35;  Kpad = 64;   Opad = 64;  tile = 0; }
    int ktiles = Kpad >> 6;
    int ot = tile / ktiles, kt = tile - ot * ktiles;
    int k0 = kt * 64, o0 = ot * 64;
    size_t LOFF = (size_t)Opad * Kpad;
    __shared__ float tl[64][68];
    int c = threadIdx.x & 63, rr = threadIdx.x >> 6;
    #pragma unroll
    for (int it = 0; it < 16; ++it) {
        int r = rr + it * 4;
        int kk = k0 + r, oo = o0 + c;
        tl[r][c] = (kk < K && oo < O) ? src[(size_t)kk * O + oo] : 0.f;
    }
    __syncthreads();
    #pragma unroll
    for (int it = 0; it < 16; ++it) {
        int r = rr + it * 4;
        float v = tl[c][r];
        __bf16 hi = (__bf16)v;
        float lo = v - (float)hi;
        size_t pos = (size_t)(o0 + r) * Kpad + k0 + c;
        dst[pos] = hi;
        dst[LOFF + pos] = (__bf16)lo;
    }
}

// ---------------------------------------------------------------------------
// MFMA conv1d, Cin=Cout=64. Output [n][t][64co] bf16. Pure-LDS K-loop.
// KCHUNK=2 keeps LDS small enough for >=2 blocks/CU (8 waves) so barrier
// drains of one block overlap the other block's MFMA.
// ---------------------------------------------------------------------------
template<int K, int STRIDE, int PAD, bool DO_BN, int IMODE,
         int NPB, int TPN, int LIN, int LOUT, int KCHUNK>
__global__ __launch_bounds__(NPB * TPN * 64, 2) void conv_mfma(
    const void* __restrict__ xin, const __bf16* __restrict__ wT,
    const float* __restrict__ bias,
    const float* __restrict__ bn_g, const float* __restrict__ bn_b,
    const float* __restrict__ bn_m, const float* __restrict__ bn_v,
    __bf16* __restrict__ y)
{
    constexpr int THREADS = NPB * TPN * 64;
    constexpr int TBLK  = TPN * 48;
    constexpr int VSPAN = STRIDE * (TBLK - 1) + K;
    constexpr int NBUF  = (STRIDE == 2) ? 2 : 1;
    constexpr int ROWS  = (VSPAN + NBUF - 1) / NBUF;
    __shared__ __align__(16) __bf16 sx[NPB * NBUF * ROWS * 72];
    __shared__ __align__(16) __bf16 sw[KCHUNK * 64 * 72];

    const int tid = threadIdx.x;
    const int nb  = blockIdx.x * NPB;

    if constexpr (IMODE == 0) {
        const float* xg = (const float*)xin + (size_t)nb * 64 * LIN;
        constexpr int NZROWS = PAD + (VSPAN - LIN - PAD);
        if (tid < NZROWS * 64) {
            int zr = tid >> 6;
            int v = (zr < PAD) ? zr : (LIN + PAD + zr - PAD);
            sx[((v & (NBUF - 1)) * ROWS + (v >> (NBUF - 1))) * 72 + (tid & 63)] = (__bf16)0.f;
        }
        constexpr int J4 = LIN / 4;
        constexpr int NCH = 64 * J4;
        constexpr int ITER = NCH / THREADS;
        #pragma unroll
        for (int it = 0; it < ITER; ++it) {
            int idx = it * THREADS + tid;
            int ci = idx / J4, j = idx - ci * J4;
            float4 f = *(const float4*)(xg + (size_t)ci * LIN + 4 * j);
            #pragma unroll
            for (int e = 0; e < 4; ++e) {
                int v = 4 * j + e + PAD;
                sx[((v & (NBUF - 1)) * ROWS + (v >> (NBUF - 1))) * 72 + ci] =
                    (__bf16)((e == 0) ? f.x : (e == 1) ? f.y : (e == 2) ? f.z : f.w);
            }
        }
    } else {
        const __bf16* xg = (const __bf16*)xin;
        constexpr int NSTG = NPB * VSPAN * 8;
        constexpr int ITER = (NSTG + THREADS - 1) / THREADS;
        #pragma unroll
        for (int it = 0; it < ITER; ++it) {
            int idx = it * THREADS + tid;
            if (idx < NSTG) {
                int n_l = idx / (VSPAN * 8);
                int r   = idx - n_l * (VSPAN * 8);
                int v = r >> 3, c8 = (r & 7) * 8;
                int buf = (STRIDE == 2) ? (v & 1) : 0;
                int row = (STRIDE == 2) ? (v >> 1) : v;
                __bf16* dst = sx + ((size_t)(n_l * NBUF + buf) * ROWS + row) * 72 + c8;
                if constexpr (IMODE == 1) {
                    if (v < LIN) {
                        const __bf16* src = xg + (((size_t)(nb + n_l) * LIN + v) * 64 + c8);
                        *(uint4*)dst = *(const uint4*)src;
                    } else {
                        #pragma unroll
                        for (int e = 0; e < 8; ++e) dst[e] = (__bf16)0.f;
                    }
                } else {
                    if (v < LIN) {
                        const __bf16* s0 = xg + (((size_t)(nb + n_l) * 82 + 2 * v) * 64 + c8);
                        #pragma unroll
                        for (int e = 0; e < 8; ++e)
                            dst[e] = (__bf16)(((float)s0[e] + (float)s0[64 + e] +
                                               (float)s0[128 + e]) * (1.f / 3.f));
                    } else {
                        #pragma unroll
                        for (int e = 0; e < 8; ++e) dst[e] = (__bf16)0.f;
                    }
                }
            }
        }
    }

    const int wave = tid >> 6, lane = tid & 63;
    const int n_l  = wave / TPN, tile = wave - n_l * TPN;
    const int m    = lane & 15, quad = lane >> 4;
    const __bf16* sxn = sx + (size_t)n_l * NBUF * ROWS * 72;

    f32x4 acc[3][4];
    #pragma unroll
    for (int mi = 0; mi < 3; ++mi)
        #pragma unroll
        for (int nj = 0; nj < 4; ++nj)
            acc[mi][nj] = (f32x4){0.f, 0.f, 0.f, 0.f};

    for (int kb = 0; kb < K; kb += KCHUNK) {
        if (kb) __syncthreads();
        constexpr int WITER = KCHUNK * 64 * 8 / THREADS;
        #pragma unroll
        for (int it = 0; it < WITER; ++it) {
            int idx = it * THREADS + tid;
            int r = idx >> 3, p = idx & 7;
            *(uint4*)(sw + (size_t)r * 72 + p * 8) =
                *(const uint4*)(wT + (size_t)(kb + (r >> 6)) * 4096 + (r & 63) * 64 + p * 8);
        }
        __syncthreads();

        #pragma unroll
        for (int kp2 = 0; kp2 < KCHUNK; ++kp2) {
            const int kp = kb + kp2;
            const int buf    = (STRIDE == 2) ? (kp & 1) : 0;
            const int rowoff = (STRIDE == 2) ? (kp >> 1) : kp;
            const __bf16* abase = sxn + ((size_t)buf * ROWS + tile * 48 + m + rowoff) * 72;
            const __bf16* bbase = sw + (size_t)(kp2 * 64 + m) * 72;
            #pragma unroll
            for (int s = 0; s < 2; ++s) {
                bf16x8 af[3], bfr[4];
                #pragma unroll
                for (int mi = 0; mi < 3; ++mi)
                    af[mi] = *(const bf16x8*)(abase + mi * (16 * 72) + s * 32 + quad * 8);
                #pragma unroll
                for (int nj = 0; nj < 4; ++nj)
                    bfr[nj] = *(const bf16x8*)(bbase + nj * (16 * 72) + s * 32 + quad * 8);
                #pragma unroll
                for (int mi = 0; mi < 3; ++mi)
                    #pragma unroll
                    for (int nj = 0; nj < 4; ++nj)
                        acc[mi][nj] = __builtin_amdgcn_mfma_f32_16x16x32_bf16(
                            af[mi], bfr[nj], acc[mi][nj], 0, 0, 0);
            }
        }
    }

    #pragma unroll
    for (int nj = 0; nj < 4; ++nj) {
        const int co = nj * 16 + m;
        const float bi = bias[co];
        float scale = 1.f, shift = 0.f;
        if constexpr (DO_BN) {
            float inv = bn_g[co] / sqrtf(bn_v[co] + 1e-5f);
            scale = inv; shift = bn_b[co] - bn_m[co] * inv;
        }
        #pragma unroll
        for (int mi = 0; mi < 3; ++mi) {
            #pragma unroll
            for (int r = 0; r < 4; ++r) {
                int t = tile * 48 + mi * 16 + quad * 4 + r;
                if (t < LOUT) {
                    float v = acc[mi][nj][r] + bi;
                    v = elu_f(v);
                    if constexpr (DO_BN) v = v * scale + shift;
                    y[((size_t)(nb + n_l) * LOUT + t) * 64 + co] = (__bf16)v;
                }
            }
        }
    }
}

// ---------------------------------------------------------------------------
// Attention pooling over crop dim. One block per (b,c). h: [512][35][64] bf16.
// ---------------------------------------------------------------------------
__global__ __launch_bounds__(256) void attn_pool_k(
    const __bf16* __restrict__ h, const float* __restrict__ W,
    const float* __restrict__ ab, const float* __restrict__ u,
    float* __restrict__ out)
{
    const int b = blockIdx.x >> 6;
    const int c = blockIdx.x & 63;
    __shared__ float sh[16 * 35];
    __shared__ float slog[16];
    __shared__ float sred[4];
    __shared__ float salpha[16];
    const int tid = threadIdx.x;
    for (int idx = tid; idx < 16 * 35; idx += 256) {
        int s = idx / 35, hh = idx - s * 35;
        sh[idx] = (float)h[((size_t)(b * 16 + s) * 35 + hh) * 64 + c];
    }
    __syncthreads();
    float Wc[35];
    #pragma unroll
    for (int k = 0; k < 35; ++k) Wc[k] = W[k * 256 + tid];
    const float myb = ab[tid], myu = u[tid];
    for (int s = 0; s < 16; ++s) {
        float dot = myb;
        #pragma unroll
        for (int k = 0; k < 35; ++k) dot = fmaf(sh[s * 35 + k], Wc[k], dot);
        float val = tanhf(dot) * myu;
        #pragma unroll
        for (int off = 32; off > 0; off >>= 1) val += __shfl_down(val, off, 64);
        if ((tid & 63) == 0) sred[tid >> 6] = val;
        __syncthreads();
        if (tid == 0) slog[s] = sred[0] + sred[1] + sred[2] + sred[3];
        __syncthreads();
    }
    if (tid == 0) {
        float mx = slog[0];
        for (int s = 1; s < 16; ++s) mx = fmaxf(mx, slog[s]);
        float sum = 0.f, e[16];
        for (int s = 0; s < 16; ++s) { e[s] = expf(slog[s] - mx); sum += e[s]; }
        float inv = 1.f / sum;
        for (int s = 0; s < 16; ++s) salpha[s] = e[s] * inv;
    }
    __syncthreads();
    if (tid < 35) {
        float acc = 0.f;
        for (int s = 0; s < 16; ++s) acc = fmaf(sh[s * 35 + tid], salpha[s], acc);
        out[((size_t)(b * 64 + c)) * 35 + tid] = elu_f(acc);
    }
}

// ---------------------------------------------------------------------------
// Fused GIN stack, split-bf16 (hi/lo) precision (3 MFMA per logical product).
// ---------------------------------------------------------------------------
#define APLANE (64 * 264)

__device__ __forceinline__ void gin_gemm_dev(
    const __bf16* As,                 // hi plane; lo at As+APLANE
    const __bf16* __restrict__ Wg, int Kpad, int wlo, int Kout,
    const float* __restrict__ bias,
    int mode,                 // 0: relu->A   1: relu, +colsum ->A   2: raw->global
    __bf16* Ad, float* __restrict__ outg)
{
    const int lane = threadIdx.x & 63;
    const int wave_o0 = (threadIdx.x >> 6) * 64;
    if (wave_o0 >= ((Kout + 63) & ~63)) return;
    const int m = lane & 15, quad = lane >> 4;

    f32x4 acc[4][4];
    #pragma unroll
    for (int mi = 0; mi < 4; ++mi)
        #pragma unroll
        for (int nj = 0; nj < 4; ++nj)
            acc[mi][nj] = (f32x4){0.f, 0.f, 0.f, 0.f};

    for (int k0 = 0; k0 < Kpad; k0 += 32) {
        bf16x8 ah[4], al[4], bh[4], bl[4];
        #pragma unroll
        for (int mi = 0; mi < 4; ++mi) {
            const __bf16* ap = As + (size_t)(mi * 16 + m) * 264 + k0 + quad * 8;
            ah[mi] = *(const bf16x8*)ap;
            al[mi] = *(const bf16x8*)(ap + APLANE);
        }
        #pragma unroll
        for (int nj = 0; nj < 4; ++nj) {
            const __bf16* wp = Wg + (size_t)(wave_o0 + nj * 16 + m) * Kpad + k0 + quad * 8;
            bh[nj] = *(const bf16x8*)wp;
            bl[nj] = *(const bf16x8*)(wp + wlo);
        }
        #pragma unroll
        for (int mi = 0; mi < 4; ++mi)
            #pragma unroll
            for (int nj = 0; nj < 4; ++nj) {
                acc[mi][nj] = __builtin_amdgcn_mfma_f32_16x16x32_bf16(
                    al[mi], bh[nj], acc[mi][nj], 0, 0, 0);
                acc[mi][nj] = __builtin_amdgcn_mfma_f32_16x16x32_bf16(
                    ah[mi], bl[nj], acc[mi][nj], 0, 0, 0);
                acc[mi][nj] = __builtin_amdgcn_mfma_f32_16x16x32_bf16(
                    ah[mi], bh[nj], acc[mi][nj], 0, 0, 0);
            }
    }

    #pragma unroll
    for (int nj = 0; nj < 4; ++nj) {
        const int o = wave_o0 + nj * 16 + m;
        const bool ovalid = (o < Kout);
        const float bi = ovalid ? bias[o] : 0.f;
        float v[4][4];
        #pragma unroll
        for (int mi = 0; mi < 4; ++mi)
            #pragma unroll
            for (int r = 0; r < 4; ++r)
                v[mi][r] = acc[mi][nj][r] + bi;
        if (mode == 2) {
            if (ovalid) {
                #pragma unroll
                for (int mi = 0; mi < 4; ++mi)
                    #pragma unroll
                    for (int r = 0; r < 4; ++r)
                        outg[(size_t)(mi * 16 + quad * 4 + r) * Kout + o] = v[mi][r];
            }
        } else {
            float s = 0.f;
            #pragma unroll
            for (int mi = 0; mi < 4; ++mi)
                #pragma unroll
                for (int r = 0; r < 4; ++r) {
                    float rv = ovalid ? fmaxf(v[mi][r], 0.f) : 0.f;
                    v[mi][r] = rv;
                    s += rv;
                }
            if (mode == 1) {
                s += __shfl_xor(s, 16, 64);
                s += __shfl_xor(s, 32, 64);
            } else {
                s = 0.f;
            }
            #pragma unroll
            for (int mi = 0; mi < 4; ++mi)
                #pragma unroll
                for (int r = 0; r < 4; ++r) {
                    float a = v[mi][r] + s;
                    __bf16 hi = (__bf16)a;
                    size_t pos = (size_t)(mi * 16 + quad * 4 + r) * 264 + o;
                    Ad[pos] = hi;
                    Ad[APLANE + pos] = (__bf16)(a - (float)hi);
                }
        }
    }
}

__global__ __launch_bounds__(256) void gin_fused(
    const float* __restrict__ ha,
    const __bf16* __restrict__ gW0a, const __bf16* __restrict__ gW0b,
    const __bf16* __restrict__ gW1a, const __bf16* __restrict__ gW1b,
    const __bf16* __restrict__ gW2a, const __bf16* __restrict__ gW2b,
    const float* __restrict__ b0a, const float* __restrict__ b0b,
    const float* __restrict__ b1a, const float* __restrict__ b1b,
    const float* __restrict__ b2a, const float* __restrict__ b2b,
    float* __restrict__ H3)
{
    const int b = blockIdx.x, tid = threadIdx.x;
    __shared__ __align__(16) __bf16 sA[2][2 * APLANE];
    __shared__ float sS[64];
    const float* hab = ha + (size_t)b * 2240;

    if (tid < 64) {
        float s = 0.f;
        if (tid < 35)
            for (int n = 0; n < 64; ++n) s += hab[n * 35 + tid];
        sS[tid] = s;
    }
    __syncthreads();
    for (int idx = tid; idx < 64 * 64; idx += 256) {
        int n = idx >> 6, k = idx & 63;
        float a = (k < 35) ? hab[n * 35 + k] + sS[k] : 0.f;
        __bf16 hi = (__bf16)a;
        sA[0][n * 264 + k] = hi;
        sA[0][APLANE + n * 264 + k] = (__bf16)(a - (float)hi);
    }
    __syncthreads();

    gin_gemm_dev(sA[0], gW0a, 64,  16384, 256, b0a, 0, sA[1], nullptr); __syncthreads();
    gin_gemm_dev(sA[1], gW0b, 256, 65536, 256, b0b, 1, sA[0], nullptr); __syncthreads();
    gin_gemm_dev(sA[0], gW1a, 256, 65536, 256, b1a, 0, sA[1], nullptr); __syncthreads();
    gin_gemm_dev(sA[1], gW1b, 256, 65536, 256, b1b, 1, sA[0], nullptr); __syncthreads();
    gin_gemm_dev(sA[0], gW2a, 256, 16384, 35,  b2a, 0, sA[1], nullptr); __syncthreads();
    gin_gemm_dev(sA[1], gW2b, 64,  4096,  35,  b2b, 2, nullptr, H3 + (size_t)b * 2240);
}

// ---------------------------------------------------------------------------
// Classifier layer 1, fp32, K-split: grid (b=32, kc=16).
// ---------------------------------------------------------------------------
__global__ __launch_bounds__(256) void cls1_part_k(
    const float* __restrict__ H3, const float* __restrict__ w1,
    float* __restrict__ s1p)
{
    const int b  = blockIdx.x;
    const int kc = blockIdx.y;
    const int k0 = kc * 140;
    __shared__ float sH[140];
    const int tid = threadIdx.x;
    if (tid < 140) sH[tid] = H3[(size_t)b * 2240 + k0 + tid];
    __syncthreads();
    const int o = (tid >> 6) * 64 + (tid & 63);
    float a0 = 0.f, a1 = 0.f, a2 = 0.f, a3 = 0.f;
    const float* wr = w1 + (size_t)k0 * 256 + o;
    #pragma unroll
    for (int k = 0; k < 140; k += 4) {
        a0 = fmaf(sH[k],     wr[(size_t)k * 256],       a0);
        a1 = fmaf(sH[k + 1], wr[(size_t)(k + 1) * 256], a1);
        a2 = fmaf(sH[k + 2], wr[(size_t)(k + 2) * 256], a2);
        a3 = fmaf(sH[k + 3], wr[(size_t)(k + 3) * 256], a3);
    }
    s1p[((size_t)kc * 32 + b) * 256 + o] = a0 + a1 + a2 + a3;
}

// ---------------------------------------------------------------------------
// Classifier: reduce K-split partials (+bias, ELU), then layers 2-4 (fp32).
// ---------------------------------------------------------------------------
__global__ __launch_bounds__(256) void cls234_k(
    const float* __restrict__ s1p, const float* __restrict__ b1,
    const float* __restrict__ w2, const float* __restrict__ b2,
    const float* __restrict__ w3, const float* __restrict__ b3,
    const float* __restrict__ w4, const float* __restrict__ b4,
    float* __restrict__ out)
{
    const int b = blockIdx.x, tid = threadIdx.x;
    __shared__ float s1[256];
    __shared__ float part[4][64];
    __shared__ float s2[64];
    __shared__ float s3[16];
    {
        float acc = b1[tid];
        #pragma unroll
        for (int kc = 0; kc < 16; ++kc)
            acc += s1p[((size_t)kc * 32 + b) * 256 + tid];
        s1[tid] = elu_f(acc);
    }
    __syncthreads();
    {
        int kg = tid >> 6, o = tid & 63;
        float acc = 0.f;
        for (int k = kg * 64; k < kg * 64 + 64; ++k)
            acc = fmaf(s1[k], w2[k * 64 + o], acc);
        part[kg][o] = acc;
    }
    __syncthreads();
    if (tid < 64) {
        float acc = part[0][tid] + part[1][tid] + part[2][tid] + part[3][tid] + b2[tid];
        s2[tid] = elu_f(acc);
    }
    __syncthreads();
    if (tid < 16) {
        float acc = b3[tid];
        for (int k = 0; k < 64; ++k) acc = fmaf(s2[k], w3[k * 16 + tid], acc);
        s3[tid] = elu_f(acc);
    }
    __syncthreads();
    if (tid < 2) {
        float acc = b4[tid];
        for (int k = 0; k < 16; ++k) acc = fmaf(s3[k], w4[k * 2 + tid], acc);
        out[b * 2 + tid] = acc;
    }
}

// ---------------------------------------------------------------------------
extern "C" void kernel_launch(void* const* d_in, const int* in_sizes, int n_in,
                              void* d_out, int out_size, void* d_ws, size_t ws_size,
                              hipStream_t stream)
{
    const float* x     = (const float*)d_in[0];
    const float* w1    = (const float*)d_in[1];
    const float* b1    = (const float*)d_in[2];
    const float* bn1_g = (const float*)d_in[3];
    const float* bn1_b = (const float*)d_in[4];
    const float* bn1_m = (const float*)d_in[5];
    const float* bn1_v = (const float*)d_in[6];
    const float* w2    = (const float*)d_in[7];
    const float* b2    = (const float*)d_in[8];
    const float* bn2_g = (const float*)d_in[9];
    const float* bn2_b = (const float*)d_in[10];
    const float* bn2_m = (const float*)d_in[11];
    const float* bn2_v = (const float*)d_in[12];
    const float* w3    = (const float*)d_in[13];
    const float* b3    = (const float*)d_in[14];
    const float* w4    = (const float*)d_in[15];
    const float* b4    = (const float*)d_in[16];
    const float* attn_w = (const float*)d_in[17];
    const float* attn_b = (const float*)d_in[18];
    const float* attn_u = (const float*)d_in[19];
    const float* g0_w1 = (const float*)d_in[20];
    const float* g0_b1 = (const float*)d_in[21];
    const float* g0_w2 = (const float*)d_in[22];
    const float* g0_b2 = (const float*)d_in[23];
    const float* g1_w1 = (const float*)d_in[24];
    const float* g1_b1 = (const float*)d_in[25];
    const float* g1_w2 = (const float*)d_in[26];
    const float* g1_b2 = (const float*)d_in[27];
    const float* g2_w1 = (const float*)d_in[28];
    const float* g2_b1 = (const float*)d_in[29];
    const float* g2_w2 = (const float*)d_in[30];
    const float* g2_b2 = (const float*)d_in[31];
    const float* c_w1  = (const float*)d_in[32];
    const float* c_b1  = (const float*)d_in[33];
    const float* c_w2  = (const float*)d_in[34];
    const float* c_b2  = (const float*)d_in[35];
    const float* c_w3  = (const float*)d_in[36];
    const float* c_b3  = (const float*)d_in[37];
    const float* c_w4  = (const float*)d_in[38];
    const float* c_b4  = (const float*)d_in[39];
    float* out = (float*)d_out;

    char* ws = (char*)d_ws;
    __bf16* wT1  = (__bf16*)(ws + 0);
    __bf16* wT2  = (__bf16*)(ws + 163840);
    __bf16* wT3  = (__bf16*)(ws + 327680);
    __bf16* wT4  = (__bf16*)(ws + 376832);
    __bf16* h1   = (__bf16*)(ws + 425984);     // [512][192][64]
    __bf16* h2   = (__bf16*)(ws + 13008896);   // [512][87][64]
    __bf16* h3   = (__bf16*)(ws + 18710528);   // [512][82][64]
    __bf16* h4   = (__bf16*)(ws + 24084480);   // [512][35][64]
    float*  ha   = (float*)(ws + 26378240);    // [32][64][35]
    __bf16* gW0a = (__bf16*)(ws + 26664960);   // hi+lo [256][64]   65536 B
    __bf16* gW0b = (__bf16*)(ws + 26730496);   // hi+lo [256][256] 262144 B
    __bf16* gW1a = (__bf16*)(ws + 26992640);
    __bf16* gW1b = (__bf16*)(ws + 27254784);
    __bf16* gW2a = (__bf16*)(ws + 27516928);   // hi+lo [64][256]   65536 B
    __bf16* gW2b = (__bf16*)(ws + 27582464);   // hi+lo [64][64]    16384 B
    float*  H3   = (float*)(ws + 27598848);    // [32][2240]
    float*  s1p  = (float*)(ws + 27885568);    // [16][32][256] = 524288 B

    prep_weights<<<dim3(832), dim3(256), 0, stream>>>(w1, w2, w3, w4, wT1, wT2, wT3, wT4);
    prep_tr<<<dim3(57), dim3(256), 0, stream>>>(g0_w1, g0_w2, g1_w1, g1_w2, g2_w1, g2_w2,
                                                gW0a, gW0b, gW1a, gW1b, gW2a, gW2b);

    // CNN stack: KCHUNK=2 keeps LDS <= ~76 KB -> 2+ blocks/CU (8 waves)
    conv_mfma<20, 2, 1, true, 0, 1, 4, 400, 192, 2><<<dim3(512), dim3(256), 0, stream>>>(
        x, wT1, b1, bn1_g, bn1_b, bn1_m, bn1_v, h1);
    conv_mfma<20, 2, 0, true, 1, 1, 2, 192, 87, 2><<<dim3(512), dim3(128), 0, stream>>>(
        h1, wT2, b2, bn2_g, bn2_b, bn2_m, bn2_v, h2);
    conv_mfma<6, 1, 0, false, 1, 1, 2, 87, 82, 2><<<dim3(512), dim3(128), 0, stream>>>(
        h2, wT3, b3, nullptr, nullptr, nullptr, nullptr, h3);
    conv_mfma<6, 1, 0, false, 2, 2, 1, 40, 35, 2><<<dim3(256), dim3(128), 0, stream>>>(
        h3, wT4, b4, nullptr, nullptr, nullptr, nullptr, h4);

    attn_pool_k<<<dim3(2048), dim3(256), 0, stream>>>(h4, attn_w, attn_b, attn_u, ha);

    gin_fused<<<dim3(32), dim3(256), 0, stream>>>(
        ha, gW0a, gW0b, gW1a, gW1b, gW2a, gW2b,
        g0_b1, g0_b2, g1_b1, g1_b2, g2_b1, g2_b2, H3);

    cls1_part_k<<<dim3(32, 16), dim3(256), 0, stream>>>(H3, c_w1, s1p);
    cls234_k<<<dim3(32), dim3(256), 0, stream>>>(s1p, c_b1, c_w2, c_b2, c_w3, c_b3,
                                                 c_w4, c_b4, out);
}